// Round 1
// baseline (2668.184 us; speedup 1.0000x reference)
//
#include <hip/hip_runtime.h>
#include <math.h>

// Problem constants
constexpr int B_  = 128;
constexpr int N_  = 1024;
constexpr int E_  = 1048576;
constexpr int BN_ = B_ * N_;      // 131072
constexpr int F_  = 64;

// ---------------- degree / normalization ----------------
// deg[dst] += 1 for each valid edge (invalid edges have src<0)
__global__ void k_deg(const int* __restrict__ src, const int* __restrict__ dst,
                      float* __restrict__ deg, int E) {
    int e = blockIdx.x * blockDim.x + threadIdx.x;
    if (e >= E) return;
    int s = src[e];
    if (s < 0) return;
    atomicAdd(&deg[dst[e]], 1.0f);
}

// in-place: dis[i] = rsqrt(deg[i] + 1)   (+1 self loop)
__global__ void k_dis(float* __restrict__ d, int n) {
    int i = blockIdx.x * blockDim.x + threadIdx.x;
    if (i >= n) return;
    d[i] = rsqrtf(d[i] + 1.0f);
}

// ---------------- xw = h @ W (64x64), fused self-loop init ----------------
// wave per row; lane = output column. Row broadcast via shuffle, W in LDS.
__global__ void k_xw_agg(const float* __restrict__ h, const float* __restrict__ W,
                         const float* __restrict__ dis, float* __restrict__ xw,
                         float* __restrict__ agg, int rows) {
    __shared__ float Wl[64 * 64];
    int tid = threadIdx.x;
    for (int i = tid; i < 4096; i += 256) Wl[i] = W[i];
    __syncthreads();
    int wave = tid >> 6, lane = tid & 63;
    int r = blockIdx.x * 4 + wave;
    if (r >= rows) return;
    float hv = h[(size_t)r * 64 + lane];
    float acc = 0.0f;
    #pragma unroll
    for (int kk = 0; kk < 64; ++kk) {
        float hk = __shfl(hv, kk, 64);
        acc = fmaf(hk, Wl[kk * 64 + lane], acc);
    }
    float d = dis[r];
    xw[(size_t)r * 64 + lane]  = acc;
    agg[(size_t)r * 64 + lane] = acc * d * d;   // self-loop message
}

// ---------------- edge aggregation (64-dim) ----------------
// 16 lanes per edge, float4 per lane.
__global__ void k_edge_agg(const int* __restrict__ src, const int* __restrict__ dst,
                           const float* __restrict__ dis, const float* __restrict__ xw,
                           float* __restrict__ agg, int E) {
    long long t = (long long)blockIdx.x * blockDim.x + threadIdx.x;
    int e  = (int)(t >> 4);
    int fq = (int)(t & 15);
    if (e >= E) return;
    int s = src[e];
    if (s < 0) return;
    int d = dst[e];
    float nrm = dis[s] * dis[d];
    const float4 v = *reinterpret_cast<const float4*>(xw + (size_t)s * 64 + fq * 4);
    float* ap = agg + (size_t)d * 64 + fq * 4;
    atomicAdd(ap + 0, v.x * nrm);
    atomicAdd(ap + 1, v.y * nrm);
    atomicAdd(ap + 2, v.z * nrm);
    atomicAdd(ap + 3, v.w * nrm);
}

// ---------------- bias + relu, in place ----------------
__global__ void k_bias_relu(float* __restrict__ a, const float* __restrict__ b, long long total) {
    long long t = (long long)blockIdx.x * blockDim.x + threadIdx.x;
    if (t >= total) return;
    int c = (int)(t & 63);
    float v = a[t] + b[c];
    a[t] = v > 0.0f ? v : 0.0f;
}

// ---------------- score conv: sxw = h @ Wp (64->1), fused self-loop ----------------
__global__ void k_score(const float* __restrict__ h, const float* __restrict__ Wp,
                        const float* __restrict__ dis, float* __restrict__ sxw,
                        float* __restrict__ sagg, int rows) {
    __shared__ float wp[64];
    if (threadIdx.x < 64) wp[threadIdx.x] = Wp[threadIdx.x];
    __syncthreads();
    int r = blockIdx.x * blockDim.x + threadIdx.x;
    if (r >= rows) return;
    const float4* hr = reinterpret_cast<const float4*>(h + (size_t)r * 64);
    float acc = 0.0f;
    #pragma unroll
    for (int kk = 0; kk < 16; ++kk) {
        float4 v = hr[kk];
        acc += v.x * wp[4*kk] + v.y * wp[4*kk+1] + v.z * wp[4*kk+2] + v.w * wp[4*kk+3];
    }
    sxw[r] = acc;
    float d = dis[r];
    sagg[r] = acc * d * d;
}

__global__ void k_score_edge(const int* __restrict__ src, const int* __restrict__ dst,
                             const float* __restrict__ dis, const float* __restrict__ sxw,
                             float* __restrict__ sagg, int E) {
    int e = blockIdx.x * blockDim.x + threadIdx.x;
    if (e >= E) return;
    int s = src[e];
    if (s < 0) return;
    int d = dst[e];
    atomicAdd(&sagg[d], sxw[s] * dis[s] * dis[d]);
}

// ---------------- per-graph top-k via bitonic sort in LDS ----------------
__global__ void k_topk(const float* __restrict__ sagg, const float* __restrict__ bp,
                       int n, int k, int* __restrict__ perm, int* __restrict__ new_idx) {
    __shared__ unsigned long long keys[1024];
    int g = blockIdx.x, tid = threadIdx.x;
    float bp0 = bp[0];
    for (int i = tid; i < 1024; i += 256) {
        unsigned long long kv = 0ull;
        if (i < n) {
            float sc = sagg[g * n + i] + bp0;
            unsigned u  = __float_as_uint(sc);
            unsigned mk = (u & 0x80000000u) ? ~u : (u | 0x80000000u);
            kv = ((unsigned long long)mk << 32) | (unsigned)i;
        }
        keys[i] = kv;
    }
    for (int size = 2; size <= 1024; size <<= 1) {
        for (int stride = size >> 1; stride > 0; stride >>= 1) {
            __syncthreads();
            for (int p = tid; p < 512; p += 256) {
                int a  = ((p / stride) * (stride << 1)) + (p & (stride - 1));
                int bx = a + stride;
                bool asc = ((a & size) == 0);
                unsigned long long ka = keys[a], kb = keys[bx];
                bool sw = asc ? (ka > kb) : (ka < kb);
                if (sw) { keys[a] = kb; keys[bx] = ka; }
            }
        }
    }
    __syncthreads();
    // ascending sort -> top-k are the last k entries
    for (int j = tid; j < k; j += 256) {
        int pos   = 1023 - j;
        int local = (int)(keys[pos] & 0xFFFFFFFFull);
        int oldg  = g * n + local;
        int newg  = g * k + j;
        perm[newg]    = oldg;
        new_idx[oldg] = newg;
    }
}

// ---------------- gather + tanh gate ----------------
__global__ void k_gather(const float* __restrict__ h, const int* __restrict__ perm,
                         const float* __restrict__ sagg, const float* __restrict__ bp,
                         float* __restrict__ xn, int rowsK) {
    long long t = (long long)blockIdx.x * blockDim.x + threadIdx.x;
    int j = (int)(t >> 6), lane = (int)(t & 63);
    if (j >= rowsK) return;
    int old = perm[j];
    float gate = tanhf(sagg[old] + bp[0]);
    xn[(size_t)j * 64 + lane] = h[(size_t)old * 64 + lane] * gate;
}

// ---------------- edge remap (invalid edges encoded as src=dst=-1) ----------------
__global__ void k_remap(const int* __restrict__ src, const int* __restrict__ dst,
                        const int* __restrict__ new_idx,
                        int* __restrict__ src2, int* __restrict__ dst2, int E) {
    int e = blockIdx.x * blockDim.x + threadIdx.x;
    if (e >= E) return;
    int s = src[e];
    int ns = -1, nd = -1;
    if (s >= 0) {
        ns = new_idx[s];
        nd = new_idx[dst[e]];
    }
    bool ok = (ns >= 0) && (nd >= 0);
    src2[e] = ok ? ns : -1;
    dst2[e] = ok ? nd : -1;
}

// ---------------- readout: concat(max, mean) accumulated into zsum ----------------
__global__ void k_readout(const float* __restrict__ xn, int k, float* __restrict__ zsum) {
    int g = blockIdx.x;
    int lane = threadIdx.x & 63, w = threadIdx.x >> 6;
    float mx = -INFINITY, sm = 0.0f;
    const float* base = xn + (size_t)g * k * 64;
    for (int j = w; j < k; j += 4) {
        float v = base[(size_t)j * 64 + lane];
        mx = fmaxf(mx, v);
        sm += v;
    }
    __shared__ float smx[4][64], ssm[4][64];
    smx[w][lane] = mx; ssm[w][lane] = sm;
    __syncthreads();
    if (w == 0) {
        for (int i = 1; i < 4; ++i) { mx = fmaxf(mx, smx[i][lane]); sm += ssm[i][lane]; }
        zsum[g * 128 + lane]      += mx;
        zsum[g * 128 + 64 + lane] += sm / (float)k;
    }
}

// ---------------- MLP head + log_softmax ----------------
__global__ void k_mlp(const float* __restrict__ zsum,
                      const float* __restrict__ L1w, const float* __restrict__ L1b,
                      const float* __restrict__ L2w, const float* __restrict__ L2b,
                      const float* __restrict__ L3w, const float* __restrict__ L3b,
                      float* __restrict__ out) {
    __shared__ float z[128], h1[64], h2[32], lg[10], lse;
    int g = blockIdx.x, tid = threadIdx.x;
    z[tid] = zsum[g * 128 + tid];
    __syncthreads();
    if (tid < 64) {
        float acc = L1b[tid];
        for (int i = 0; i < 128; ++i) acc = fmaf(z[i], L1w[i * 64 + tid], acc);
        h1[tid] = fmaxf(acc, 0.0f);
    }
    __syncthreads();
    if (tid < 32) {
        float acc = L2b[tid];
        for (int i = 0; i < 64; ++i) acc = fmaf(h1[i], L2w[i * 32 + tid], acc);
        h2[tid] = fmaxf(acc, 0.0f);
    }
    __syncthreads();
    if (tid < 10) {
        float acc = L3b[tid];
        for (int i = 0; i < 32; ++i) acc = fmaf(h2[i], L3w[i * 10 + tid], acc);
        lg[tid] = acc;
    }
    __syncthreads();
    if (tid == 0) {
        float m = lg[0];
        for (int i = 1; i < 10; ++i) m = fmaxf(m, lg[i]);
        float s = 0.0f;
        for (int i = 0; i < 10; ++i) s += expf(lg[i] - m);
        lse = m + logf(s);
    }
    __syncthreads();
    if (tid < 10) out[g * 10 + tid] = lg[tid] - lse;
}

// ---------------- launcher ----------------
extern "C" void kernel_launch(void* const* d_in, const int* in_sizes, int n_in,
                              void* d_out, int out_size, void* d_ws, size_t ws_size,
                              hipStream_t stream) {
    const float* x    = (const float*)d_in[0];
    const int*   esrc = (const int*)d_in[1];
    const int*   edst = (const int*)d_in[2];
    const float* W [3] = {(const float*)d_in[3],  (const float*)d_in[7],  (const float*)d_in[11]};
    const float* bb[3] = {(const float*)d_in[4],  (const float*)d_in[8],  (const float*)d_in[12]};
    const float* Wp[3] = {(const float*)d_in[5],  (const float*)d_in[9],  (const float*)d_in[13]};
    const float* bp[3] = {(const float*)d_in[6],  (const float*)d_in[10], (const float*)d_in[14]};
    const float* L1w = (const float*)d_in[15];
    const float* L1b = (const float*)d_in[16];
    const float* L2w = (const float*)d_in[17];
    const float* L2b = (const float*)d_in[18];
    const float* L3w = (const float*)d_in[19];
    const float* L3b = (const float*)d_in[20];
    float* out = (float*)d_out;

    // workspace carve (floats)
    float* fws  = (float*)d_ws;
    float* bufA = fws;                   // pooled features (B*k*64), max 8388608
    float* xw   = bufA + 8388608;
    float* agg  = xw   + 8388608;
    float* dis  = agg  + 8388608;        // deg -> dis, B*n
    float* sxw  = dis  + BN_;
    float* sagg = sxw  + BN_;
    float* zsum = sagg + BN_;            // 128*128
    int*   new_idx = (int*)(zsum + 128 * 128);
    int*   perm    = new_idx + BN_;
    int*   srcB    = perm + BN_;
    int*   dstB    = srcB + E_;
    int*   srcC    = dstB + E_;
    int*   dstC    = srcC + E_;

    hipMemsetAsync(zsum, 0, 128 * 128 * sizeof(float), stream);

    const int ks_[3] = {820, 656, 525};   // ceil(0.8*1024), ceil(0.8*820), ceil(0.8*656)
    int n = N_;
    const float* h_in = x;
    const int* cs = esrc;
    const int* cd = edst;
    int* nsrc[2] = {srcB, srcC};
    int* ndst[2] = {dstB, dstC};

    const int EB = (E_ + 255) / 256;   // 4096 blocks for per-edge kernels

    for (int L = 0; L < 3; ++L) {
        int rows  = B_ * n;
        int k     = ks_[L];
        int rowsK = B_ * k;

        // degree + normalization
        hipMemsetAsync(dis, 0, (size_t)rows * sizeof(float), stream);
        k_deg<<<EB, 256, 0, stream>>>(cs, cd, dis, E_);
        k_dis<<<(rows + 255) / 256, 256, 0, stream>>>(dis, rows);

        // conv
        k_xw_agg<<<(rows + 3) / 4, 256, 0, stream>>>(h_in, W[L], dis, xw, agg, rows);
        {
            long long tt = (long long)E_ * 16;
            k_edge_agg<<<(unsigned)((tt + 255) / 256), 256, 0, stream>>>(cs, cd, dis, xw, agg, E_);
        }
        {
            long long tt = (long long)rows * 64;
            k_bias_relu<<<(unsigned)((tt + 255) / 256), 256, 0, stream>>>(agg, bb[L], tt);
        }

        // score conv (reuses dis: same edges/mask)
        k_score<<<(rows + 255) / 256, 256, 0, stream>>>(agg, Wp[L], dis, sxw, sagg, rows);
        k_score_edge<<<EB, 256, 0, stream>>>(cs, cd, dis, sxw, sagg, E_);

        // pool
        if (L < 2) hipMemsetAsync(new_idx, 0xFF, (size_t)rows * sizeof(int), stream);
        k_topk<<<B_, 256, 0, stream>>>(sagg, bp[L], n, k, perm, new_idx);
        {
            long long tt = (long long)rowsK * 64;
            k_gather<<<(unsigned)((tt + 255) / 256), 256, 0, stream>>>(agg, perm, sagg, bp[L], bufA, rowsK);
        }
        if (L < 2) k_remap<<<EB, 256, 0, stream>>>(cs, cd, new_idx, nsrc[L], ndst[L], E_);

        // readout accumulate
        k_readout<<<B_, 256, 0, stream>>>(bufA, k, zsum);

        // next layer
        h_in = bufA;
        n = k;
        if (L < 2) { cs = nsrc[L]; cd = ndst[L]; }
    }

    k_mlp<<<B_, 128, 0, stream>>>(zsum, L1w, L1b, L2w, L2b, L3w, L3b, out);
}

// Round 2
// 1464.242 us; speedup vs baseline: 1.8222x; 1.8222x over previous
//
#include <hip/hip_runtime.h>
#include <math.h>

// Problem constants
constexpr int B_  = 128;
constexpr int N_  = 1024;
constexpr int E_  = 1048576;
constexpr int BN_ = B_ * N_;      // 131072
constexpr int EPG = E_ / B_;      // 8192 edges per graph (contiguous, preserved by remap)

// ---------------- per-graph degree histogram + rsqrt norm ----------------
__global__ void k_deg_dis(const int* __restrict__ src, const int* __restrict__ dst,
                          float* __restrict__ dis, int n) {
    __shared__ int cnt[1024];
    int g = blockIdx.x, tid = threadIdx.x;
    int base = g * n;
    for (int i = tid; i < n; i += 256) cnt[i] = 0;
    __syncthreads();
    for (int t = tid; t < EPG; t += 256) {
        int e = g * EPG + t;
        if (src[e] >= 0) atomicAdd(&cnt[dst[e] - base], 1);
    }
    __syncthreads();
    for (int i = tid; i < n; i += 256)
        dis[base + i] = rsqrtf((float)cnt[i] + 1.0f);
}

// ---------------- xw = h @ W (64x64) ----------------
// wave per row; lane = output column. Row broadcast via shuffle, W in LDS.
__global__ void k_xw(const float* __restrict__ h, const float* __restrict__ W,
                     float* __restrict__ xw, int rows) {
    __shared__ float Wl[64 * 64];
    int tid = threadIdx.x;
    for (int i = tid; i < 4096; i += 256) Wl[i] = W[i];
    __syncthreads();
    int wave = tid >> 6, lane = tid & 63;
    int r = blockIdx.x * 4 + wave;
    if (r >= rows) return;
    float hv = h[(size_t)r * 64 + lane];
    float acc = 0.0f;
    #pragma unroll
    for (int kk = 0; kk < 64; ++kk) {
        float hk = __shfl(hv, kk, 64);
        acc = fmaf(hk, Wl[kk * 64 + lane], acc);
    }
    xw[(size_t)r * 64 + lane] = acc;
}

// ---------------- edge aggregation in LDS ----------------
// one WG per (graph, feature-half). LDS tile: n x 32 floats, row stride 33
// (bank = (row + f) % 32 -> spreads random dst rows across banks).
// Init = self-loop xw*dis^2; edges accumulate via ds atomics; write-out fuses
// bias + ReLU (conv output h).
__global__ __launch_bounds__(1024) void k_edge_agg_lds(
        const int* __restrict__ src, const int* __restrict__ dst,
        const float* __restrict__ dis, const float* __restrict__ xw,
        const float* __restrict__ bias, float* __restrict__ hout, int n) {
    extern __shared__ float la[];                    // n * 33 floats
    int g    = blockIdx.x >> 1;
    int foff = (blockIdx.x & 1) * 32;
    int tid  = threadIdx.x;
    int base = g * n;

    for (int i = tid; i < n * 32; i += 1024) {
        int row = i >> 5, f = i & 31;
        float d = dis[base + row];
        la[row * 33 + f] = xw[(size_t)(base + row) * 64 + foff + f] * d * d;
    }
    __syncthreads();

    const int ebase = g * EPG;
    for (int t = tid; t < EPG * 8; t += 1024) {      // 8 lanes per edge, float4 each
        int e = ebase + (t >> 3);
        int sub = t & 7;
        int s = src[e];
        if (s < 0) continue;
        int d = dst[e];
        float nrm = dis[s] * dis[d];
        const float4 v = *reinterpret_cast<const float4*>(xw + (size_t)s * 64 + foff + sub * 4);
        float* ap = la + (d - base) * 33 + sub * 4;
        atomicAdd(ap + 0, v.x * nrm);
        atomicAdd(ap + 1, v.y * nrm);
        atomicAdd(ap + 2, v.z * nrm);
        atomicAdd(ap + 3, v.w * nrm);
    }
    __syncthreads();

    for (int i = tid; i < n * 32; i += 1024) {
        int row = i >> 5, f = i & 31;
        float v = la[row * 33 + f] + bias[foff + f];
        hout[(size_t)(base + row) * 64 + foff + f] = fmaxf(v, 0.0f);
    }
}

// ---------------- score conv: sxw = h @ Wp (64->1) ----------------
__global__ void k_score(const float* __restrict__ h, const float* __restrict__ Wp,
                        float* __restrict__ sxw, int rows) {
    __shared__ float wp[64];
    if (threadIdx.x < 64) wp[threadIdx.x] = Wp[threadIdx.x];
    __syncthreads();
    int r = blockIdx.x * blockDim.x + threadIdx.x;
    if (r >= rows) return;
    const float4* hr = reinterpret_cast<const float4*>(h + (size_t)r * 64);
    float acc = 0.0f;
    #pragma unroll
    for (int kk = 0; kk < 16; ++kk) {
        float4 v = hr[kk];
        acc += v.x * wp[4*kk] + v.y * wp[4*kk+1] + v.z * wp[4*kk+2] + v.w * wp[4*kk+3];
    }
    sxw[r] = acc;
}

// ---------------- score edge aggregation in LDS (self-loop fused) ----------------
__global__ void k_score_edge_lds(const int* __restrict__ src, const int* __restrict__ dst,
                                 const float* __restrict__ dis, const float* __restrict__ sxw,
                                 float* __restrict__ sagg, int n) {
    __shared__ float ls[1024];
    int g = blockIdx.x, tid = threadIdx.x;
    int base = g * n;
    for (int i = tid; i < n; i += 256) {
        float d = dis[base + i];
        ls[i] = sxw[base + i] * d * d;
    }
    __syncthreads();
    for (int t = tid; t < EPG; t += 256) {
        int e = g * EPG + t;
        int s = src[e];
        if (s < 0) continue;
        int d = dst[e];
        atomicAdd(&ls[d - base], sxw[s] * dis[s] * dis[d]);
    }
    __syncthreads();
    for (int i = tid; i < n; i += 256) sagg[base + i] = ls[i];
}

// ---------------- per-graph top-k via bitonic sort in LDS ----------------
__global__ void k_topk(const float* __restrict__ sagg, const float* __restrict__ bp,
                       int n, int k, int* __restrict__ perm, int* __restrict__ new_idx) {
    __shared__ unsigned long long keys[1024];
    int g = blockIdx.x, tid = threadIdx.x;
    float bp0 = bp[0];
    for (int i = tid; i < 1024; i += 256) {
        unsigned long long kv = 0ull;
        if (i < n) {
            float sc = sagg[g * n + i] + bp0;
            unsigned u  = __float_as_uint(sc);
            unsigned mk = (u & 0x80000000u) ? ~u : (u | 0x80000000u);
            kv = ((unsigned long long)mk << 32) | (unsigned)i;
        }
        keys[i] = kv;
    }
    for (int size = 2; size <= 1024; size <<= 1) {
        for (int stride = size >> 1; stride > 0; stride >>= 1) {
            __syncthreads();
            for (int p = tid; p < 512; p += 256) {
                int a  = ((p / stride) * (stride << 1)) + (p & (stride - 1));
                int bx = a + stride;
                bool asc = ((a & size) == 0);
                unsigned long long ka = keys[a], kb = keys[bx];
                bool sw = asc ? (ka > kb) : (ka < kb);
                if (sw) { keys[a] = kb; keys[bx] = ka; }
            }
        }
    }
    __syncthreads();
    for (int j = tid; j < k; j += 256) {
        int pos   = 1023 - j;
        int local = (int)(keys[pos] & 0xFFFFFFFFull);
        int oldg  = g * n + local;
        int newg  = g * k + j;
        perm[newg]    = oldg;
        new_idx[oldg] = newg;
    }
}

// ---------------- gather + tanh gate ----------------
__global__ void k_gather(const float* __restrict__ h, const int* __restrict__ perm,
                         const float* __restrict__ sagg, const float* __restrict__ bp,
                         float* __restrict__ xn, int rowsK) {
    long long t = (long long)blockIdx.x * blockDim.x + threadIdx.x;
    int j = (int)(t >> 6), lane = (int)(t & 63);
    if (j >= rowsK) return;
    int old = perm[j];
    float gate = tanhf(sagg[old] + bp[0]);
    xn[(size_t)j * 64 + lane] = h[(size_t)old * 64 + lane] * gate;
}

// ---------------- edge remap (invalid edges encoded as src=dst=-1) ----------------
__global__ void k_remap(const int* __restrict__ src, const int* __restrict__ dst,
                        const int* __restrict__ new_idx,
                        int* __restrict__ src2, int* __restrict__ dst2, int E) {
    int e = blockIdx.x * blockDim.x + threadIdx.x;
    if (e >= E) return;
    int s = src[e];
    int ns = -1, nd = -1;
    if (s >= 0) {
        ns = new_idx[s];
        nd = new_idx[dst[e]];
    }
    bool ok = (ns >= 0) && (nd >= 0);
    src2[e] = ok ? ns : -1;
    dst2[e] = ok ? nd : -1;
}

// ---------------- readout: concat(max, mean) accumulated into zsum ----------------
__global__ void k_readout(const float* __restrict__ xn, int k, float* __restrict__ zsum) {
    int g = blockIdx.x;
    int lane = threadIdx.x & 63, w = threadIdx.x >> 6;
    float mx = -INFINITY, sm = 0.0f;
    const float* base = xn + (size_t)g * k * 64;
    for (int j = w; j < k; j += 4) {
        float v = base[(size_t)j * 64 + lane];
        mx = fmaxf(mx, v);
        sm += v;
    }
    __shared__ float smx[4][64], ssm[4][64];
    smx[w][lane] = mx; ssm[w][lane] = sm;
    __syncthreads();
    if (w == 0) {
        for (int i = 1; i < 4; ++i) { mx = fmaxf(mx, smx[i][lane]); sm += ssm[i][lane]; }
        zsum[g * 128 + lane]      += mx;
        zsum[g * 128 + 64 + lane] += sm / (float)k;
    }
}

// ---------------- MLP head + log_softmax ----------------
__global__ void k_mlp(const float* __restrict__ zsum,
                      const float* __restrict__ L1w, const float* __restrict__ L1b,
                      const float* __restrict__ L2w, const float* __restrict__ L2b,
                      const float* __restrict__ L3w, const float* __restrict__ L3b,
                      float* __restrict__ out) {
    __shared__ float z[128], h1[64], h2[32], lg[10], lse;
    int g = blockIdx.x, tid = threadIdx.x;
    z[tid] = zsum[g * 128 + tid];
    __syncthreads();
    if (tid < 64) {
        float acc = L1b[tid];
        for (int i = 0; i < 128; ++i) acc = fmaf(z[i], L1w[i * 64 + tid], acc);
        h1[tid] = fmaxf(acc, 0.0f);
    }
    __syncthreads();
    if (tid < 32) {
        float acc = L2b[tid];
        for (int i = 0; i < 64; ++i) acc = fmaf(h1[i], L2w[i * 32 + tid], acc);
        h2[tid] = fmaxf(acc, 0.0f);
    }
    __syncthreads();
    if (tid < 10) {
        float acc = L3b[tid];
        for (int i = 0; i < 32; ++i) acc = fmaf(h2[i], L3w[i * 10 + tid], acc);
        lg[tid] = acc;
    }
    __syncthreads();
    if (tid == 0) {
        float m = lg[0];
        for (int i = 1; i < 10; ++i) m = fmaxf(m, lg[i]);
        float s = 0.0f;
        for (int i = 0; i < 10; ++i) s += expf(lg[i] - m);
        lse = m + logf(s);
    }
    __syncthreads();
    if (tid < 10) out[g * 10 + tid] = lg[tid] - lse;
}

// ---------------- launcher ----------------
extern "C" void kernel_launch(void* const* d_in, const int* in_sizes, int n_in,
                              void* d_out, int out_size, void* d_ws, size_t ws_size,
                              hipStream_t stream) {
    const float* x    = (const float*)d_in[0];
    const int*   esrc = (const int*)d_in[1];
    const int*   edst = (const int*)d_in[2];
    const float* W [3] = {(const float*)d_in[3],  (const float*)d_in[7],  (const float*)d_in[11]};
    const float* bb[3] = {(const float*)d_in[4],  (const float*)d_in[8],  (const float*)d_in[12]};
    const float* Wp[3] = {(const float*)d_in[5],  (const float*)d_in[9],  (const float*)d_in[13]};
    const float* bp[3] = {(const float*)d_in[6],  (const float*)d_in[10], (const float*)d_in[14]};
    const float* L1w = (const float*)d_in[15];
    const float* L1b = (const float*)d_in[16];
    const float* L2w = (const float*)d_in[17];
    const float* L2b = (const float*)d_in[18];
    const float* L3w = (const float*)d_in[19];
    const float* L3b = (const float*)d_in[20];
    float* out = (float*)d_out;

    // workspace carve (floats)
    float* fws  = (float*)d_ws;
    float* bufA = fws;                   // pooled features (B*k*64), max 8388608
    float* xw   = bufA + 8388608;
    float* agg  = xw   + 8388608;        // conv output h
    float* dis  = agg  + 8388608;        // B*n
    float* sxw  = dis  + BN_;
    float* sagg = sxw  + BN_;
    float* zsum = sagg + BN_;            // 128*128
    int*   new_idx = (int*)(zsum + 128 * 128);
    int*   perm    = new_idx + BN_;
    int*   srcB    = perm + BN_;
    int*   dstB    = srcB + E_;
    int*   srcC    = dstB + E_;
    int*   dstC    = srcC + E_;

    // allow >64KB dynamic LDS for the aggregation kernel
    static bool attr_set = false;
    hipFuncSetAttribute(reinterpret_cast<const void*>(k_edge_agg_lds),
                        hipFuncAttributeMaxDynamicSharedMemorySize, 1024 * 33 * 4);
    (void)attr_set;

    hipMemsetAsync(zsum, 0, 128 * 128 * sizeof(float), stream);

    const int ks_[3] = {820, 656, 525};   // ceil(0.8*1024), ceil(0.8*820), ceil(0.8*656)
    int n = N_;
    const float* h_in = x;
    const int* cs = esrc;
    const int* cd = edst;
    int* nsrc[2] = {srcB, srcC};
    int* ndst[2] = {dstB, dstC};

    const int EB = (E_ + 255) / 256;   // 4096 blocks for per-edge kernels

    for (int L = 0; L < 3; ++L) {
        int rows  = B_ * n;
        int k     = ks_[L];
        int rowsK = B_ * k;

        // degree + normalization (per-graph LDS histogram)
        k_deg_dis<<<B_, 256, 0, stream>>>(cs, cd, dis, n);

        // conv: xw then LDS edge aggregation (fused self-loop + bias + relu)
        k_xw<<<(rows + 3) / 4, 256, 0, stream>>>(h_in, W[L], xw, rows);
        k_edge_agg_lds<<<B_ * 2, 1024, (size_t)n * 33 * 4, stream>>>(
            cs, cd, dis, xw, bb[L], agg, n);

        // score conv (reuses dis: same edges/mask)
        k_score<<<(rows + 255) / 256, 256, 0, stream>>>(agg, Wp[L], sxw, rows);
        k_score_edge_lds<<<B_, 256, 0, stream>>>(cs, cd, dis, sxw, sagg, n);

        // pool
        if (L < 2) hipMemsetAsync(new_idx, 0xFF, (size_t)rows * sizeof(int), stream);
        k_topk<<<B_, 256, 0, stream>>>(sagg, bp[L], n, k, perm, new_idx);
        {
            long long tt = (long long)rowsK * 64;
            k_gather<<<(unsigned)((tt + 255) / 256), 256, 0, stream>>>(agg, perm, sagg, bp[L], bufA, rowsK);
        }
        if (L < 2) k_remap<<<EB, 256, 0, stream>>>(cs, cd, new_idx, nsrc[L], ndst[L], E_);

        // readout accumulate
        k_readout<<<B_, 256, 0, stream>>>(bufA, k, zsum);

        // next layer
        h_in = bufA;
        n = k;
        if (L < 2) { cs = nsrc[L]; cd = ndst[L]; }
    }

    k_mlp<<<B_, 128, 0, stream>>>(zsum, L1w, L1b, L2w, L2b, L3w, L3b, out);
}

// Round 3
// 1442.216 us; speedup vs baseline: 1.8501x; 1.0153x over previous
//
#include <hip/hip_runtime.h>
#include <math.h>

// Problem constants
constexpr int B_  = 128;
constexpr int N_  = 1024;
constexpr int E_  = 1048576;
constexpr int BN_ = B_ * N_;      // 131072
constexpr int EPG = E_ / B_;      // 8192 edges per graph (contiguous, preserved by remap)

// ---------------- per-graph degree histogram + rsqrt norm ----------------
__global__ __launch_bounds__(1024) void k_deg_dis(
        const int* __restrict__ src, const int* __restrict__ dst,
        float* __restrict__ dis, int n) {
    __shared__ int cnt[1024];
    int g = blockIdx.x, tid = threadIdx.x;
    int base = g * n;
    for (int i = tid; i < n; i += 1024) cnt[i] = 0;
    __syncthreads();
    for (int t = tid; t < EPG; t += 1024) {
        int e = g * EPG + t;
        if (src[e] >= 0) atomicAdd(&cnt[dst[e] - base], 1);
    }
    __syncthreads();
    for (int i = tid; i < n; i += 1024)
        dis[base + i] = rsqrtf((float)cnt[i] + 1.0f);
}

// ---------------- xws = (h @ W) * dis, written in quarter-plane layout ----------------
// wave per row, 8 rows per wave. Quarter-plane: xwq[(q*rows + r)*16 + f], q=f64>>4.
__global__ __launch_bounds__(1024) void k_xw_q(
        const float* __restrict__ h, const float* __restrict__ W,
        const float* __restrict__ dis, float* __restrict__ xwq, int rows) {
    __shared__ float Wl[64 * 64];
    int tid = threadIdx.x;
    for (int i = tid; i < 4096; i += 1024) Wl[i] = W[i];
    __syncthreads();
    int wave = tid >> 6, lane = tid & 63;
    int q = lane >> 4, f = lane & 15;
    int r0 = blockIdx.x * 128 + wave * 8;
    #pragma unroll
    for (int j = 0; j < 8; ++j) {
        int r = r0 + j;
        float hv = h[(size_t)r * 64 + lane];
        float acc = 0.0f;
        #pragma unroll
        for (int kk = 0; kk < 64; ++kk) {
            float hk = __shfl(hv, kk, 64);
            acc = fmaf(hk, Wl[kk * 64 + lane], acc);
        }
        acc *= dis[r];
        xwq[((size_t)q * rows + r) * 16 + f] = acc;
    }
}

// ---------------- edge aggregation fully in LDS ----------------
// block = (graph, feature-quarter). LDS: xws plane (n x 16, stride 20) +
// accumulator plane (n x 16, stride 17). Hot loop: coalesced edge reads,
// ds_read_b128 gather + 4x ds_add. Writeout fuses dis scale + bias + ReLU.
__global__ __launch_bounds__(1024) void k_agg_lds(
        const int* __restrict__ src, const int* __restrict__ dst,
        const float* __restrict__ dis, const float* __restrict__ xwq,
        const float* __restrict__ bias, float* __restrict__ hout,
        int n, int rows) {
    extern __shared__ float lds[];
    float* xs = lds;             // n * 20
    float* ac = lds + n * 20;    // n * 17
    int g = blockIdx.x >> 2, q = blockIdx.x & 3;
    int foff = q * 16;
    int tid  = threadIdx.x;
    int base = g * n;
    const float* plane = xwq + ((size_t)q * rows + base) * 16;

    for (int i = tid; i < n * 4; i += 1024) {
        int row = i >> 2, sub = i & 3;
        float4 v = *reinterpret_cast<const float4*>(plane + row * 16 + sub * 4);
        *reinterpret_cast<float4*>(xs + row * 20 + sub * 4) = v;
        float* ap = ac + row * 17 + sub * 4;
        ap[0] = v.x; ap[1] = v.y; ap[2] = v.z; ap[3] = v.w;   // self-loop init
    }
    __syncthreads();

    const int ebase = g * EPG;
    for (int t = tid; t < EPG * 4; t += 1024) {
        int e = ebase + (t >> 2);
        int sub = t & 3;
        int s = src[e];
        if (s < 0) continue;
        int d = dst[e];
        const float4 v = *reinterpret_cast<const float4*>(xs + (s - base) * 20 + sub * 4);
        float* ap = ac + (d - base) * 17 + sub * 4;
        atomicAdd(ap + 0, v.x);
        atomicAdd(ap + 1, v.y);
        atomicAdd(ap + 2, v.z);
        atomicAdd(ap + 3, v.w);
    }
    __syncthreads();

    for (int i = tid; i < n * 16; i += 1024) {
        int row = i >> 4, f = i & 15;
        float v = dis[base + row] * ac[row * 17 + f] + bias[foff + f];
        hout[(size_t)(base + row) * 64 + foff + f] = fmaxf(v, 0.0f);
    }
}

// ---------------- score conv: sxws = (h @ Wp) * dis ----------------
__global__ void k_score(const float* __restrict__ h, const float* __restrict__ Wp,
                        const float* __restrict__ dis, float* __restrict__ sxws, int rows) {
    __shared__ float wp[64];
    if (threadIdx.x < 64) wp[threadIdx.x] = Wp[threadIdx.x];
    __syncthreads();
    int r = blockIdx.x * blockDim.x + threadIdx.x;
    if (r >= rows) return;
    const float4* hr = reinterpret_cast<const float4*>(h + (size_t)r * 64);
    float acc = 0.0f;
    #pragma unroll
    for (int kk = 0; kk < 16; ++kk) {
        float4 v = hr[kk];
        acc += v.x * wp[4*kk] + v.y * wp[4*kk+1] + v.z * wp[4*kk+2] + v.w * wp[4*kk+3];
    }
    sxws[r] = acc * dis[r];
}

// ---------------- score edge aggregation in LDS ----------------
__global__ __launch_bounds__(1024) void k_score_edge_lds(
        const int* __restrict__ src, const int* __restrict__ dst,
        const float* __restrict__ dis, const float* __restrict__ sxws,
        float* __restrict__ sagg, int n) {
    __shared__ float xs[1024];
    __shared__ float ac[1024];
    int g = blockIdx.x, tid = threadIdx.x;
    int base = g * n;
    for (int i = tid; i < n; i += 1024) {
        float v = sxws[base + i];
        xs[i] = v; ac[i] = v;
    }
    __syncthreads();
    for (int t = tid; t < EPG; t += 1024) {
        int e = g * EPG + t;
        int s = src[e];
        if (s < 0) continue;
        atomicAdd(&ac[dst[e] - base], xs[s - base]);
    }
    __syncthreads();
    for (int i = tid; i < n; i += 1024) sagg[base + i] = dis[base + i] * ac[i];
}

// ---------------- per-graph top-k via bitonic sort in LDS ----------------
__global__ __launch_bounds__(512) void k_topk(
        const float* __restrict__ sagg, const float* __restrict__ bp,
        int n, int k, int* __restrict__ perm, int* __restrict__ new_idx) {
    __shared__ unsigned long long keys[1024];
    int g = blockIdx.x, tid = threadIdx.x;
    float bp0 = bp[0];
    for (int i = tid; i < 1024; i += 512) {
        unsigned long long kv = 0ull;
        if (i < n) {
            float sc = sagg[g * n + i] + bp0;
            unsigned u  = __float_as_uint(sc);
            unsigned mk = (u & 0x80000000u) ? ~u : (u | 0x80000000u);
            kv = ((unsigned long long)mk << 32) | (unsigned)i;
        }
        keys[i] = kv;
    }
    for (int size = 2; size <= 1024; size <<= 1) {
        for (int stride = size >> 1; stride > 0; stride >>= 1) {
            __syncthreads();
            int p = tid;                           // 512 threads = 512 pairs
            int a  = ((p / stride) * (stride << 1)) + (p & (stride - 1));
            int bx = a + stride;
            bool asc = ((a & size) == 0);
            unsigned long long ka = keys[a], kb = keys[bx];
            bool sw = asc ? (ka > kb) : (ka < kb);
            if (sw) { keys[a] = kb; keys[bx] = ka; }
        }
    }
    __syncthreads();
    for (int j = tid; j < k; j += 512) {
        int pos   = 1023 - j;
        int local = (int)(keys[pos] & 0xFFFFFFFFull);
        int oldg  = g * n + local;
        int newg  = g * k + j;
        perm[newg]    = oldg;
        new_idx[oldg] = newg;
    }
}

// ---------------- gather + tanh gate ----------------
__global__ void k_gather(const float* __restrict__ h, const int* __restrict__ perm,
                         const float* __restrict__ sagg, const float* __restrict__ bp,
                         float* __restrict__ xn, int rowsK) {
    long long t = (long long)blockIdx.x * blockDim.x + threadIdx.x;
    int j = (int)(t >> 6), lane = (int)(t & 63);
    if (j >= rowsK) return;
    int old = perm[j];
    float gate = tanhf(sagg[old] + bp[0]);
    xn[(size_t)j * 64 + lane] = h[(size_t)old * 64 + lane] * gate;
}

// ---------------- edge remap (invalid edges encoded as src=dst=-1) ----------------
__global__ void k_remap(const int* __restrict__ src, const int* __restrict__ dst,
                        const int* __restrict__ new_idx,
                        int* __restrict__ src2, int* __restrict__ dst2, int E) {
    int e = blockIdx.x * blockDim.x + threadIdx.x;
    if (e >= E) return;
    int s = src[e];
    int ns = -1, nd = -1;
    if (s >= 0) {
        ns = new_idx[s];
        nd = new_idx[dst[e]];
    }
    bool ok = (ns >= 0) && (nd >= 0);
    src2[e] = ok ? ns : -1;
    dst2[e] = ok ? nd : -1;
}

// ---------------- readout: concat(max, mean) accumulated into zsum ----------------
__global__ void k_readout(const float* __restrict__ xn, int k, float* __restrict__ zsum) {
    int g = blockIdx.x;
    int lane = threadIdx.x & 63, w = threadIdx.x >> 6;
    float mx = -INFINITY, sm = 0.0f;
    const float* base = xn + (size_t)g * k * 64;
    for (int j = w; j < k; j += 4) {
        float v = base[(size_t)j * 64 + lane];
        mx = fmaxf(mx, v);
        sm += v;
    }
    __shared__ float smx[4][64], ssm[4][64];
    smx[w][lane] = mx; ssm[w][lane] = sm;
    __syncthreads();
    if (w == 0) {
        for (int i = 1; i < 4; ++i) { mx = fmaxf(mx, smx[i][lane]); sm += ssm[i][lane]; }
        zsum[g * 128 + lane]      += mx;
        zsum[g * 128 + 64 + lane] += sm / (float)k;
    }
}

// ---------------- MLP head + log_softmax ----------------
__global__ void k_mlp(const float* __restrict__ zsum,
                      const float* __restrict__ L1w, const float* __restrict__ L1b,
                      const float* __restrict__ L2w, const float* __restrict__ L2b,
                      const float* __restrict__ L3w, const float* __restrict__ L3b,
                      float* __restrict__ out) {
    __shared__ float z[128], h1[64], h2[32], lg[10], lse;
    int g = blockIdx.x, tid = threadIdx.x;
    z[tid] = zsum[g * 128 + tid];
    __syncthreads();
    if (tid < 64) {
        float acc = L1b[tid];
        for (int i = 0; i < 128; ++i) acc = fmaf(z[i], L1w[i * 64 + tid], acc);
        h1[tid] = fmaxf(acc, 0.0f);
    }
    __syncthreads();
    if (tid < 32) {
        float acc = L2b[tid];
        for (int i = 0; i < 64; ++i) acc = fmaf(h1[i], L2w[i * 32 + tid], acc);
        h2[tid] = fmaxf(acc, 0.0f);
    }
    __syncthreads();
    if (tid < 10) {
        float acc = L3b[tid];
        for (int i = 0; i < 32; ++i) acc = fmaf(h2[i], L3w[i * 10 + tid], acc);
        lg[tid] = acc;
    }
    __syncthreads();
    if (tid == 0) {
        float m = lg[0];
        for (int i = 1; i < 10; ++i) m = fmaxf(m, lg[i]);
        float s = 0.0f;
        for (int i = 0; i < 10; ++i) s += expf(lg[i] - m);
        lse = m + logf(s);
    }
    __syncthreads();
    if (tid < 10) out[g * 10 + tid] = lg[tid] - lse;
}

// ---------------- launcher ----------------
extern "C" void kernel_launch(void* const* d_in, const int* in_sizes, int n_in,
                              void* d_out, int out_size, void* d_ws, size_t ws_size,
                              hipStream_t stream) {
    const float* x    = (const float*)d_in[0];
    const int*   esrc = (const int*)d_in[1];
    const int*   edst = (const int*)d_in[2];
    const float* W [3] = {(const float*)d_in[3],  (const float*)d_in[7],  (const float*)d_in[11]};
    const float* bb[3] = {(const float*)d_in[4],  (const float*)d_in[8],  (const float*)d_in[12]};
    const float* Wp[3] = {(const float*)d_in[5],  (const float*)d_in[9],  (const float*)d_in[13]};
    const float* bp[3] = {(const float*)d_in[6],  (const float*)d_in[10], (const float*)d_in[14]};
    const float* L1w = (const float*)d_in[15];
    const float* L1b = (const float*)d_in[16];
    const float* L2w = (const float*)d_in[17];
    const float* L2b = (const float*)d_in[18];
    const float* L3w = (const float*)d_in[19];
    const float* L3b = (const float*)d_in[20];
    float* out = (float*)d_out;

    // workspace carve (floats)
    float* fws  = (float*)d_ws;
    float* bufA = fws;                   // pooled features (B*k*64), max 8388608
    float* xwq  = bufA + 8388608;        // quarter-plane xws, rows*64 floats
    float* agg  = xwq  + 8388608;        // conv output h
    float* dis  = agg  + 8388608;        // B*n
    float* sxws = dis  + BN_;
    float* sagg = sxws + BN_;
    float* zsum = sagg + BN_;            // 128*128
    int*   new_idx = (int*)(zsum + 128 * 128);
    int*   perm    = new_idx + BN_;
    int*   srcB    = perm + BN_;
    int*   dstB    = srcB + E_;
    int*   srcC    = dstB + E_;
    int*   dstC    = srcC + E_;

    // allow >64KB dynamic LDS for the aggregation kernel (max n=1024: 151552B)
    hipFuncSetAttribute(reinterpret_cast<const void*>(k_agg_lds),
                        hipFuncAttributeMaxDynamicSharedMemorySize, 1024 * 37 * 4);

    hipMemsetAsync(zsum, 0, 128 * 128 * sizeof(float), stream);

    const int ks_[3] = {820, 656, 525};   // ceil(0.8*1024), ceil(0.8*820), ceil(0.8*656)
    int n = N_;
    const float* h_in = x;
    const int* cs = esrc;
    const int* cd = edst;
    int* nsrc[2] = {srcB, srcC};
    int* ndst[2] = {dstB, dstC};

    const int EB = (E_ + 255) / 256;

    for (int L = 0; L < 3; ++L) {
        int rows  = B_ * n;
        int k     = ks_[L];
        int rowsK = B_ * k;

        // degree + normalization (per-graph LDS histogram)
        k_deg_dis<<<B_, 1024, 0, stream>>>(cs, cd, dis, n);

        // conv: xws (pre-scaled, quarter layout) then LDS-resident aggregation
        k_xw_q<<<rows / 128, 1024, 0, stream>>>(h_in, W[L], dis, xwq, rows);
        k_agg_lds<<<B_ * 4, 1024, (size_t)n * 37 * 4, stream>>>(
            cs, cd, dis, xwq, bb[L], agg, n, rows);

        // score conv (pre-scaled) + LDS aggregation
        k_score<<<(rows + 255) / 256, 256, 0, stream>>>(agg, Wp[L], dis, sxws, rows);
        k_score_edge_lds<<<B_, 1024, 0, stream>>>(cs, cd, dis, sxws, sagg, n);

        // pool
        if (L < 2) hipMemsetAsync(new_idx, 0xFF, (size_t)rows * sizeof(int), stream);
        k_topk<<<B_, 512, 0, stream>>>(sagg, bp[L], n, k, perm, new_idx);
        {
            long long tt = (long long)rowsK * 64;
            k_gather<<<(unsigned)((tt + 255) / 256), 256, 0, stream>>>(agg, perm, sagg, bp[L], bufA, rowsK);
        }
        if (L < 2) k_remap<<<EB, 256, 0, stream>>>(cs, cd, new_idx, nsrc[L], ndst[L], E_);

        // readout accumulate
        k_readout<<<B_, 256, 0, stream>>>(bufA, k, zsum);

        // next layer
        h_in = bufA;
        n = k;
        if (L < 2) { cs = nsrc[L]; cd = ndst[L]; }
    }

    k_mlp<<<B_, 128, 0, stream>>>(zsum, L1w, L1b, L2w, L2b, L3w, L3b, out);
}

// Round 4
// 772.267 us; speedup vs baseline: 3.4550x; 1.8675x over previous
//
#include <hip/hip_runtime.h>
#include <math.h>

// Problem constants
constexpr int B_  = 128;
constexpr int N_  = 1024;
constexpr int E_  = 1048576;
constexpr int BN_ = B_ * N_;      // 131072
constexpr int EPG = E_ / B_;      // 8192 edges per graph (contiguous, preserved by remap)

// ---------------- per-graph CSR build (counting sort by dst) ----------------
// Also emits dis = rsqrt(deg+1). 1 block per graph, 1024 threads.
__global__ __launch_bounds__(1024) void k_csr(
        const int* __restrict__ src, const int* __restrict__ dst,
        int* __restrict__ srt, int* __restrict__ rowptr,
        float* __restrict__ dis, int n) {
    __shared__ int cnt[1024];
    __shared__ int cur[1024];
    __shared__ int wsum[17];
    int g = blockIdx.x, tid = threadIdx.x;
    int base = g * n;
    const int eb = g * EPG;

    for (int i = tid; i < n; i += 1024) cnt[i] = 0;
    __syncthreads();
    for (int t = tid; t < EPG; t += 1024) {
        int s = src[eb + t];
        if (s >= 0) atomicAdd(&cnt[dst[eb + t] - base], 1);
    }
    __syncthreads();

    // block-wide exclusive scan of cnt[0..n) (zeros beyond n)
    int c = (tid < n) ? cnt[tid] : 0;
    int v = c;
    int lane = tid & 63, wv = tid >> 6;
    #pragma unroll
    for (int off = 1; off < 64; off <<= 1) {
        int t = __shfl_up(v, off, 64);
        if (lane >= off) v += t;
    }
    if (lane == 63) wsum[wv] = v;
    __syncthreads();
    if (tid == 0) {
        int run = 0;
        #pragma unroll
        for (int i = 0; i < 16; ++i) { int t = wsum[i]; wsum[i] = run; run += t; }
        wsum[16] = run;
    }
    __syncthreads();
    int excl = v - c + wsum[wv];
    if (tid < n) {
        cur[tid] = excl;
        rowptr[g * (n + 1) + tid] = excl;
        dis[base + tid] = rsqrtf((float)c + 1.0f);
    }
    if (tid == 0) rowptr[g * (n + 1) + n] = wsum[16];
    __syncthreads();

    // scatter local src indices grouped by dst
    for (int t = tid; t < EPG; t += 1024) {
        int s = src[eb + t];
        if (s < 0) continue;
        int pos = atomicAdd(&cur[dst[eb + t] - base], 1);
        srt[eb + pos] = s - base;
    }
}

// ---------------- xws = (h @ W) * dis, written in quarter-plane layout ----------------
// wave per row, 8 rows per wave. Quarter-plane: xwq[(q*rows + r)*16 + f], q=f64>>4.
__global__ __launch_bounds__(1024) void k_xw_q(
        const float* __restrict__ h, const float* __restrict__ W,
        const float* __restrict__ dis, float* __restrict__ xwq, int rows) {
    __shared__ float Wl[64 * 64];
    int tid = threadIdx.x;
    for (int i = tid; i < 4096; i += 1024) Wl[i] = W[i];
    __syncthreads();
    int wave = tid >> 6, lane = tid & 63;
    int q = lane >> 4, f = lane & 15;
    int r0 = blockIdx.x * 128 + wave * 8;
    #pragma unroll
    for (int j = 0; j < 8; ++j) {
        int r = r0 + j;
        float hv = h[(size_t)r * 64 + lane];
        float acc = 0.0f;
        #pragma unroll
        for (int kk = 0; kk < 64; ++kk) {
            float hk = __shfl(hv, kk, 64);
            acc = fmaf(hk, Wl[kk * 64 + lane], acc);
        }
        acc *= dis[r];
        xwq[((size_t)q * rows + r) * 16 + f] = acc;
    }
}

// ---------------- CSR edge aggregation, atomic-free ----------------
// block = (graph, feature-quarter). LDS: xs plane (n x 16, stride 20) +
// sorted src list + rowptr. Each dst row owned by 4 threads (float4 each),
// register accumulation, one write. Writeout fuses dis scale + bias + ReLU.
__global__ __launch_bounds__(1024) void k_agg_csr(
        const int* __restrict__ srt, const int* __restrict__ rowptr,
        const float* __restrict__ dis, const float* __restrict__ xwq,
        const float* __restrict__ bias, float* __restrict__ hout,
        int n, int rows) {
    extern __shared__ float lds[];
    float* xs  = lds;                       // n * 20
    int* lsrt  = (int*)(lds + n * 20);      // EPG
    int* lrp   = lsrt + EPG;                // n + 1
    int g = blockIdx.x >> 2, q = blockIdx.x & 3;
    int foff = q * 16;
    int tid  = threadIdx.x;
    int base = g * n;
    const float* plane = xwq + ((size_t)q * rows + base) * 16;

    for (int i = tid; i < n * 4; i += 1024) {
        int row = i >> 2, sub = i & 3;
        float4 v = *reinterpret_cast<const float4*>(plane + row * 16 + sub * 4);
        *reinterpret_cast<float4*>(xs + row * 20 + sub * 4) = v;
    }
    for (int i = tid; i <= n; i += 1024) lrp[i] = rowptr[g * (n + 1) + i];
    __syncthreads();
    int total = lrp[n];
    const int* gsrt = srt + g * EPG;
    for (int i = tid; i < total; i += 1024) lsrt[i] = gsrt[i];
    __syncthreads();

    int sub = tid & 3;
    float4 b = *reinterpret_cast<const float4*>(bias + foff + sub * 4);
    for (int row = tid >> 2; row < n; row += 256) {
        int s0 = lrp[row], s1 = lrp[row + 1];
        float4 acc = *reinterpret_cast<const float4*>(xs + row * 20 + sub * 4); // self-loop
        for (int j = s0; j < s1; ++j) {
            int s = lsrt[j];
            const float4 v = *reinterpret_cast<const float4*>(xs + s * 20 + sub * 4);
            acc.x += v.x; acc.y += v.y; acc.z += v.z; acc.w += v.w;
        }
        float dsc = dis[base + row];
        float4 o;
        o.x = fmaxf(fmaf(dsc, acc.x, b.x), 0.0f);
        o.y = fmaxf(fmaf(dsc, acc.y, b.y), 0.0f);
        o.z = fmaxf(fmaf(dsc, acc.z, b.z), 0.0f);
        o.w = fmaxf(fmaf(dsc, acc.w, b.w), 0.0f);
        *reinterpret_cast<float4*>(hout + (size_t)(base + row) * 64 + foff + sub * 4) = o;
    }
}

// ---------------- score conv: sxws = (h @ Wp) * dis ----------------
__global__ void k_score(const float* __restrict__ h, const float* __restrict__ Wp,
                        const float* __restrict__ dis, float* __restrict__ sxws, int rows) {
    __shared__ float wp[64];
    if (threadIdx.x < 64) wp[threadIdx.x] = Wp[threadIdx.x];
    __syncthreads();
    int r = blockIdx.x * blockDim.x + threadIdx.x;
    if (r >= rows) return;
    const float4* hr = reinterpret_cast<const float4*>(h + (size_t)r * 64);
    float acc = 0.0f;
    #pragma unroll
    for (int kk = 0; kk < 16; ++kk) {
        float4 v = hr[kk];
        acc += v.x * wp[4*kk] + v.y * wp[4*kk+1] + v.z * wp[4*kk+2] + v.w * wp[4*kk+3];
    }
    sxws[r] = acc * dis[r];
}

// ---------------- CSR score aggregation, atomic-free ----------------
__global__ __launch_bounds__(1024) void k_score_csr(
        const int* __restrict__ srt, const int* __restrict__ rowptr,
        const float* __restrict__ dis, const float* __restrict__ sxws,
        float* __restrict__ sagg, int n) {
    __shared__ float xs[1024];
    __shared__ int lrp[1025];
    __shared__ int lsrt[EPG];
    int g = blockIdx.x, tid = threadIdx.x;
    int base = g * n;
    for (int i = tid; i < n; i += 1024) xs[i] = sxws[base + i];
    for (int i = tid; i <= n; i += 1024) lrp[i] = rowptr[g * (n + 1) + i];
    __syncthreads();
    int total = lrp[n];
    for (int i = tid; i < total; i += 1024) lsrt[i] = srt[g * EPG + i];
    __syncthreads();
    if (tid < n) {
        float acc = xs[tid];                 // self loop
        int s1 = lrp[tid + 1];
        for (int j = lrp[tid]; j < s1; ++j) acc += xs[lsrt[j]];
        sagg[base + tid] = dis[base + tid] * acc;
    }
}

// ---------------- per-graph top-k via bitonic sort in LDS ----------------
__global__ __launch_bounds__(512) void k_topk(
        const float* __restrict__ sagg, const float* __restrict__ bp,
        int n, int k, int* __restrict__ perm, int* __restrict__ new_idx) {
    __shared__ unsigned long long keys[1024];
    int g = blockIdx.x, tid = threadIdx.x;
    float bp0 = bp[0];
    for (int i = tid; i < 1024; i += 512) {
        unsigned long long kv = 0ull;
        if (i < n) {
            float sc = sagg[g * n + i] + bp0;
            unsigned u  = __float_as_uint(sc);
            unsigned mk = (u & 0x80000000u) ? ~u : (u | 0x80000000u);
            kv = ((unsigned long long)mk << 32) | (unsigned)i;
        }
        keys[i] = kv;
    }
    for (int size = 2; size <= 1024; size <<= 1) {
        for (int stride = size >> 1; stride > 0; stride >>= 1) {
            __syncthreads();
            int p = tid;
            int a  = ((p / stride) * (stride << 1)) + (p & (stride - 1));
            int bx = a + stride;
            bool asc = ((a & size) == 0);
            unsigned long long ka = keys[a], kb = keys[bx];
            bool sw = asc ? (ka > kb) : (ka < kb);
            if (sw) { keys[a] = kb; keys[bx] = ka; }
        }
    }
    __syncthreads();
    for (int j = tid; j < k; j += 512) {
        int pos   = 1023 - j;
        int local = (int)(keys[pos] & 0xFFFFFFFFull);
        int oldg  = g * n + local;
        int newg  = g * k + j;
        perm[newg]    = oldg;
        new_idx[oldg] = newg;
    }
}

// ---------------- gather + tanh gate ----------------
__global__ void k_gather(const float* __restrict__ h, const int* __restrict__ perm,
                         const float* __restrict__ sagg, const float* __restrict__ bp,
                         float* __restrict__ xn, int rowsK) {
    long long t = (long long)blockIdx.x * blockDim.x + threadIdx.x;
    int j = (int)(t >> 6), lane = (int)(t & 63);
    if (j >= rowsK) return;
    int old = perm[j];
    float gate = tanhf(sagg[old] + bp[0]);
    xn[(size_t)j * 64 + lane] = h[(size_t)old * 64 + lane] * gate;
}

// ---------------- edge remap (invalid edges encoded as src=dst=-1) ----------------
__global__ void k_remap(const int* __restrict__ src, const int* __restrict__ dst,
                        const int* __restrict__ new_idx,
                        int* __restrict__ src2, int* __restrict__ dst2, int E) {
    int e = blockIdx.x * blockDim.x + threadIdx.x;
    if (e >= E) return;
    int s = src[e];
    int ns = -1, nd = -1;
    if (s >= 0) {
        ns = new_idx[s];
        nd = new_idx[dst[e]];
    }
    bool ok = (ns >= 0) && (nd >= 0);
    src2[e] = ok ? ns : -1;
    dst2[e] = ok ? nd : -1;
}

// ---------------- readout: concat(max, mean) accumulated into zsum ----------------
__global__ void k_readout(const float* __restrict__ xn, int k, float* __restrict__ zsum) {
    int g = blockIdx.x;
    int lane = threadIdx.x & 63, w = threadIdx.x >> 6;
    float mx = -INFINITY, sm = 0.0f;
    const float* base = xn + (size_t)g * k * 64;
    for (int j = w; j < k; j += 4) {
        float v = base[(size_t)j * 64 + lane];
        mx = fmaxf(mx, v);
        sm += v;
    }
    __shared__ float smx[4][64], ssm[4][64];
    smx[w][lane] = mx; ssm[w][lane] = sm;
    __syncthreads();
    if (w == 0) {
        for (int i = 1; i < 4; ++i) { mx = fmaxf(mx, smx[i][lane]); sm += ssm[i][lane]; }
        zsum[g * 128 + lane]      += mx;
        zsum[g * 128 + 64 + lane] += sm / (float)k;
    }
}

// ---------------- MLP head + log_softmax ----------------
__global__ void k_mlp(const float* __restrict__ zsum,
                      const float* __restrict__ L1w, const float* __restrict__ L1b,
                      const float* __restrict__ L2w, const float* __restrict__ L2b,
                      const float* __restrict__ L3w, const float* __restrict__ L3b,
                      float* __restrict__ out) {
    __shared__ float z[128], h1[64], h2[32], lg[10], lse;
    int g = blockIdx.x, tid = threadIdx.x;
    z[tid] = zsum[g * 128 + tid];
    __syncthreads();
    if (tid < 64) {
        float acc = L1b[tid];
        for (int i = 0; i < 128; ++i) acc = fmaf(z[i], L1w[i * 64 + tid], acc);
        h1[tid] = fmaxf(acc, 0.0f);
    }
    __syncthreads();
    if (tid < 32) {
        float acc = L2b[tid];
        for (int i = 0; i < 64; ++i) acc = fmaf(h1[i], L2w[i * 32 + tid], acc);
        h2[tid] = fmaxf(acc, 0.0f);
    }
    __syncthreads();
    if (tid < 10) {
        float acc = L3b[tid];
        for (int i = 0; i < 32; ++i) acc = fmaf(h2[i], L3w[i * 10 + tid], acc);
        lg[tid] = acc;
    }
    __syncthreads();
    if (tid == 0) {
        float m = lg[0];
        for (int i = 1; i < 10; ++i) m = fmaxf(m, lg[i]);
        float s = 0.0f;
        for (int i = 0; i < 10; ++i) s += expf(lg[i] - m);
        lse = m + logf(s);
    }
    __syncthreads();
    if (tid < 10) out[g * 10 + tid] = lg[tid] - lse;
}

// ---------------- launcher ----------------
extern "C" void kernel_launch(void* const* d_in, const int* in_sizes, int n_in,
                              void* d_out, int out_size, void* d_ws, size_t ws_size,
                              hipStream_t stream) {
    const float* x    = (const float*)d_in[0];
    const int*   esrc = (const int*)d_in[1];
    const int*   edst = (const int*)d_in[2];
    const float* W [3] = {(const float*)d_in[3],  (const float*)d_in[7],  (const float*)d_in[11]};
    const float* bb[3] = {(const float*)d_in[4],  (const float*)d_in[8],  (const float*)d_in[12]};
    const float* Wp[3] = {(const float*)d_in[5],  (const float*)d_in[9],  (const float*)d_in[13]};
    const float* bp[3] = {(const float*)d_in[6],  (const float*)d_in[10], (const float*)d_in[14]};
    const float* L1w = (const float*)d_in[15];
    const float* L1b = (const float*)d_in[16];
    const float* L2w = (const float*)d_in[17];
    const float* L2b = (const float*)d_in[18];
    const float* L3w = (const float*)d_in[19];
    const float* L3b = (const float*)d_in[20];
    float* out = (float*)d_out;

    // workspace carve (words)
    float* fws  = (float*)d_ws;
    float* bufA = fws;                   // pooled features, max B*820*64 = 6,717,440
    float* xwq  = bufA + 6717440;        // quarter-plane xws, rows*64
    float* agg  = xwq  + 8388608;        // conv output h
    float* dis  = agg  + 8388608;        // B*n
    float* sxws = dis  + BN_;
    float* sagg = sxws + BN_;
    float* zsum = sagg + BN_;            // 128*128
    int*   new_idx = (int*)(zsum + 128 * 128);
    int*   perm    = new_idx + BN_;
    int*   srcB    = perm + BN_;
    int*   dstB    = srcB + E_;
    int*   srcC    = dstB + E_;
    int*   dstC    = srcC + E_;
    int*   srt     = dstC + E_;          // sorted-by-dst local src indices (per layer)
    int*   rowptr  = srt  + E_;          // B * (n+1)

    // allow >64KB dynamic LDS for the aggregation kernel (max n=1024: 118788B)
    hipFuncSetAttribute(reinterpret_cast<const void*>(k_agg_csr),
                        hipFuncAttributeMaxDynamicSharedMemorySize,
                        (1024 * 20 + EPG + 1025) * 4);

    hipMemsetAsync(zsum, 0, 128 * 128 * sizeof(float), stream);

    const int ks_[3] = {820, 656, 525};   // ceil(0.8*1024), ceil(0.8*820), ceil(0.8*656)
    int n = N_;
    const float* h_in = x;
    const int* cs = esrc;
    const int* cd = edst;
    int* nsrc[2] = {srcB, srcC};
    int* ndst[2] = {dstB, dstC};

    const int EB = (E_ + 255) / 256;

    for (int L = 0; L < 3; ++L) {
        int rows  = B_ * n;
        int k     = ks_[L];
        int rowsK = B_ * k;

        // CSR build (also computes dis)
        k_csr<<<B_, 1024, 0, stream>>>(cs, cd, srt, rowptr, dis, n);

        // conv: xws (pre-scaled, quarter layout) then CSR aggregation
        k_xw_q<<<rows / 128, 1024, 0, stream>>>(h_in, W[L], dis, xwq, rows);
        k_agg_csr<<<B_ * 4, 1024, (size_t)(n * 20 + EPG + n + 1) * 4, stream>>>(
            srt, rowptr, dis, xwq, bb[L], agg, n, rows);

        // score conv (pre-scaled) + CSR aggregation
        k_score<<<(rows + 255) / 256, 256, 0, stream>>>(agg, Wp[L], dis, sxws, rows);
        k_score_csr<<<B_, 1024, 0, stream>>>(srt, rowptr, dis, sxws, sagg, n);

        // pool
        if (L < 2) hipMemsetAsync(new_idx, 0xFF, (size_t)rows * sizeof(int), stream);
        k_topk<<<B_, 512, 0, stream>>>(sagg, bp[L], n, k, perm, new_idx);
        {
            long long tt = (long long)rowsK * 64;
            k_gather<<<(unsigned)((tt + 255) / 256), 256, 0, stream>>>(agg, perm, sagg, bp[L], bufA, rowsK);
        }
        if (L < 2) k_remap<<<EB, 256, 0, stream>>>(cs, cd, new_idx, nsrc[L], ndst[L], E_);

        // readout accumulate
        k_readout<<<B_, 256, 0, stream>>>(bufA, k, zsum);

        // next layer
        h_in = bufA;
        n = k;
        if (L < 2) { cs = nsrc[L]; cd = ndst[L]; }
    }

    k_mlp<<<B_, 128, 0, stream>>>(zsum, L1w, L1b, L2w, L2b, L3w, L3b, out);
}

// Round 5
// 532.609 us; speedup vs baseline: 5.0097x; 1.4500x over previous
//
#include <hip/hip_runtime.h>
#include <math.h>

// Problem constants
constexpr int B_  = 128;
constexpr int N_  = 1024;
constexpr int E_  = 1048576;
constexpr int BN_ = B_ * N_;      // 131072
constexpr int EPG = E_ / B_;      // 8192 edges per graph (contiguous, preserved by remap)

typedef short v8s __attribute__((ext_vector_type(8)));
typedef float v4f __attribute__((ext_vector_type(4)));

__device__ __forceinline__ unsigned bf16_rne(unsigned u) {
    return (u + 0x7FFFu + ((u >> 16) & 1u)) >> 16;
}

// ---------------- per-graph CSR build (counting sort by dst) ----------------
// Also emits dis = rsqrt(deg+1). 1 block per graph, 1024 threads.
__global__ __launch_bounds__(1024) void k_csr(
        const int* __restrict__ src, const int* __restrict__ dst,
        int* __restrict__ srt, int* __restrict__ rowptr,
        float* __restrict__ dis, int n) {
    __shared__ int cnt[1024];
    __shared__ int cur[1024];
    __shared__ int wsum[17];
    int g = blockIdx.x, tid = threadIdx.x;
    int base = g * n;
    const int eb = g * EPG;

    for (int i = tid; i < n; i += 1024) cnt[i] = 0;
    __syncthreads();
    for (int t = tid; t < EPG; t += 1024) {
        int s = src[eb + t];
        if (s >= 0) atomicAdd(&cnt[dst[eb + t] - base], 1);
    }
    __syncthreads();

    // block-wide exclusive scan of cnt[0..n) (zeros beyond n)
    int c = (tid < n) ? cnt[tid] : 0;
    int v = c;
    int lane = tid & 63, wv = tid >> 6;
    #pragma unroll
    for (int off = 1; off < 64; off <<= 1) {
        int t = __shfl_up(v, off, 64);
        if (lane >= off) v += t;
    }
    if (lane == 63) wsum[wv] = v;
    __syncthreads();
    if (tid == 0) {
        int run = 0;
        #pragma unroll
        for (int i = 0; i < 16; ++i) { int t = wsum[i]; wsum[i] = run; run += t; }
        wsum[16] = run;
    }
    __syncthreads();
    int excl = v - c + wsum[wv];
    if (tid < n) {
        cur[tid] = excl;
        rowptr[g * (n + 1) + tid] = excl;
        dis[base + tid] = rsqrtf((float)c + 1.0f);
    }
    if (tid == 0) rowptr[g * (n + 1) + n] = wsum[16];
    __syncthreads();

    // scatter local src indices grouped by dst
    for (int t = tid; t < EPG; t += 1024) {
        int s = src[eb + t];
        if (s < 0) continue;
        int pos = atomicAdd(&cur[dst[eb + t] - base], 1);
        srt[eb + pos] = s - base;
    }
}

// ---------------- W fragment prep: split-bf16 per-lane MFMA layout ----------------
// wf[((p*4 + c)*2 + kk)*64 + lane][j] : bf16 of W[kk*32 + (lane>>4)*8 + j][c*16 + (lane&15)]
// p=0: hi, p=1: lo. 1024 threads, one thread per (p,c,kk,lane).
__global__ __launch_bounds__(1024) void k_wprep(const float* __restrict__ W,
                                                unsigned short* __restrict__ wf) {
    int t = threadIdx.x;
    int l  = t & 63;
    int kk = (t >> 6) & 1;
    int c  = (t >> 7) & 3;
    int p  = (t >> 9) & 1;
    int col = c * 16 + (l & 15);
    int kbase = kk * 32 + (l >> 4) * 8;
    unsigned short o[8];
    #pragma unroll
    for (int j = 0; j < 8; ++j) {
        float w = W[(kbase + j) * 64 + col];
        unsigned u  = __float_as_uint(w);
        unsigned hi = bf16_rne(u);
        if (p == 0) o[j] = (unsigned short)hi;
        else {
            float lo = w - __uint_as_float(hi << 16);
            o[j] = (unsigned short)bf16_rne(__float_as_uint(lo));
        }
    }
    uint4 v;
    v.x = o[0] | ((unsigned)o[1] << 16);
    v.y = o[2] | ((unsigned)o[3] << 16);
    v.z = o[4] | ((unsigned)o[5] << 16);
    v.w = o[6] | ((unsigned)o[7] << 16);
    *reinterpret_cast<uint4*>(wf + (size_t)t * 8) = v;
}

// ---------------- xws = (h @ W) * dis via split-bf16 MFMA ----------------
// 256 threads = 4 waves; block covers 128 rows (2 x 16-row tiles per wave).
// Output in quarter-plane layout: xwq[(c*rows + r)*16 + col].
__global__ __launch_bounds__(256) void k_xw_mfma(
        const float* __restrict__ h, const unsigned short* __restrict__ wf,
        const float* __restrict__ dis, float* __restrict__ xwq, int rows) {
    __shared__ float hs[128][68];
    __shared__ float sdis[128];
    int tid = threadIdx.x;
    int r0 = blockIdx.x * 128;

    for (int i = tid; i < 128 * 16; i += 256) {
        int row = i >> 4, s = i & 15;
        float4 v = *reinterpret_cast<const float4*>(h + (size_t)(r0 + row) * 64 + s * 4);
        *reinterpret_cast<float4*>(&hs[row][s * 4]) = v;
    }
    if (tid < 128) sdis[tid] = dis[r0 + tid];

    int lane = tid & 63;
    v8s wh[4][2], wl[4][2];
    #pragma unroll
    for (int c = 0; c < 4; ++c) {
        #pragma unroll
        for (int kk = 0; kk < 2; ++kk) {
            wh[c][kk] = *reinterpret_cast<const v8s*>(wf + (((size_t)((0*4 + c)*2 + kk))*64 + lane)*8);
            wl[c][kk] = *reinterpret_cast<const v8s*>(wf + (((size_t)((1*4 + c)*2 + kk))*64 + lane)*8);
        }
    }
    __syncthreads();

    int wave = tid >> 6;
    int m = lane & 15, b = lane >> 4;
    #pragma unroll
    for (int t = 0; t < 2; ++t) {
        int lr0 = (wave * 2 + t) * 16;
        float f[16];
        *reinterpret_cast<float4*>(f)      = *reinterpret_cast<const float4*>(&hs[lr0 + m][b * 8]);
        *reinterpret_cast<float4*>(f + 4)  = *reinterpret_cast<const float4*>(&hs[lr0 + m][b * 8 + 4]);
        *reinterpret_cast<float4*>(f + 8)  = *reinterpret_cast<const float4*>(&hs[lr0 + m][32 + b * 8]);
        *reinterpret_cast<float4*>(f + 12) = *reinterpret_cast<const float4*>(&hs[lr0 + m][32 + b * 8 + 4]);
        v8s ah[2], al[2];
        #pragma unroll
        for (int ch = 0; ch < 2; ++ch) {
            #pragma unroll
            for (int j = 0; j < 8; ++j) {
                float x = f[ch * 8 + j];
                unsigned u  = __float_as_uint(x);
                unsigned hi = bf16_rne(u);
                float lo = x - __uint_as_float(hi << 16);
                ah[ch][j] = (short)hi;
                al[ch][j] = (short)bf16_rne(__float_as_uint(lo));
            }
        }
        float dv[4];
        #pragma unroll
        for (int reg = 0; reg < 4; ++reg) dv[reg] = sdis[lr0 + b * 4 + reg];

        #pragma unroll
        for (int c = 0; c < 4; ++c) {
            v4f acc = {0.f, 0.f, 0.f, 0.f};
            acc = __builtin_amdgcn_mfma_f32_16x16x32_bf16(ah[0], wh[c][0], acc, 0, 0, 0);
            acc = __builtin_amdgcn_mfma_f32_16x16x32_bf16(ah[1], wh[c][1], acc, 0, 0, 0);
            acc = __builtin_amdgcn_mfma_f32_16x16x32_bf16(al[0], wh[c][0], acc, 0, 0, 0);
            acc = __builtin_amdgcn_mfma_f32_16x16x32_bf16(al[1], wh[c][1], acc, 0, 0, 0);
            acc = __builtin_amdgcn_mfma_f32_16x16x32_bf16(ah[0], wl[c][0], acc, 0, 0, 0);
            acc = __builtin_amdgcn_mfma_f32_16x16x32_bf16(ah[1], wl[c][1], acc, 0, 0, 0);
            acc = __builtin_amdgcn_mfma_f32_16x16x32_bf16(al[0], wl[c][0], acc, 0, 0, 0);
            acc = __builtin_amdgcn_mfma_f32_16x16x32_bf16(al[1], wl[c][1], acc, 0, 0, 0);
            #pragma unroll
            for (int reg = 0; reg < 4; ++reg) {
                int grow = r0 + lr0 + b * 4 + reg;
                xwq[((size_t)c * rows + grow) * 16 + m] = acc[reg] * dv[reg];
            }
        }
    }
}

// ---------------- CSR edge aggregation, atomic-free ----------------
__global__ __launch_bounds__(1024) void k_agg_csr(
        const int* __restrict__ srt, const int* __restrict__ rowptr,
        const float* __restrict__ dis, const float* __restrict__ xwq,
        const float* __restrict__ bias, float* __restrict__ hout,
        int n, int rows) {
    extern __shared__ float lds[];
    float* xs  = lds;                       // n * 20
    int* lsrt  = (int*)(lds + n * 20);      // EPG
    int* lrp   = lsrt + EPG;                // n + 1
    int g = blockIdx.x >> 2, q = blockIdx.x & 3;
    int foff = q * 16;
    int tid  = threadIdx.x;
    int base = g * n;
    const float* plane = xwq + ((size_t)q * rows + base) * 16;

    for (int i = tid; i < n * 4; i += 1024) {
        int row = i >> 2, sub = i & 3;
        float4 v = *reinterpret_cast<const float4*>(plane + row * 16 + sub * 4);
        *reinterpret_cast<float4*>(xs + row * 20 + sub * 4) = v;
    }
    for (int i = tid; i <= n; i += 1024) lrp[i] = rowptr[g * (n + 1) + i];
    __syncthreads();
    int total = lrp[n];
    const int* gsrt = srt + g * EPG;
    for (int i = tid; i < total; i += 1024) lsrt[i] = gsrt[i];
    __syncthreads();

    int sub = tid & 3;
    float4 b = *reinterpret_cast<const float4*>(bias + foff + sub * 4);
    for (int row = tid >> 2; row < n; row += 256) {
        int s0 = lrp[row], s1 = lrp[row + 1];
        float4 acc = *reinterpret_cast<const float4*>(xs + row * 20 + sub * 4); // self-loop
        for (int j = s0; j < s1; ++j) {
            int s = lsrt[j];
            const float4 v = *reinterpret_cast<const float4*>(xs + s * 20 + sub * 4);
            acc.x += v.x; acc.y += v.y; acc.z += v.z; acc.w += v.w;
        }
        float dsc = dis[base + row];
        float4 o;
        o.x = fmaxf(fmaf(dsc, acc.x, b.x), 0.0f);
        o.y = fmaxf(fmaf(dsc, acc.y, b.y), 0.0f);
        o.z = fmaxf(fmaf(dsc, acc.z, b.z), 0.0f);
        o.w = fmaxf(fmaf(dsc, acc.w, b.w), 0.0f);
        *reinterpret_cast<float4*>(hout + (size_t)(base + row) * 64 + foff + sub * 4) = o;
    }
}

// ---------------- score conv: sxws = (h @ Wp) * dis ----------------
__global__ void k_score(const float* __restrict__ h, const float* __restrict__ Wp,
                        const float* __restrict__ dis, float* __restrict__ sxws, int rows) {
    __shared__ float wp[64];
    if (threadIdx.x < 64) wp[threadIdx.x] = Wp[threadIdx.x];
    __syncthreads();
    int r = blockIdx.x * blockDim.x + threadIdx.x;
    if (r >= rows) return;
    const float4* hr = reinterpret_cast<const float4*>(h + (size_t)r * 64);
    float acc = 0.0f;
    #pragma unroll
    for (int kk = 0; kk < 16; ++kk) {
        float4 v = hr[kk];
        acc += v.x * wp[4*kk] + v.y * wp[4*kk+1] + v.z * wp[4*kk+2] + v.w * wp[4*kk+3];
    }
    sxws[r] = acc * dis[r];
}

// ---------------- CSR score aggregation, atomic-free ----------------
__global__ __launch_bounds__(1024) void k_score_csr(
        const int* __restrict__ srt, const int* __restrict__ rowptr,
        const float* __restrict__ dis, const float* __restrict__ sxws,
        float* __restrict__ sagg, int n) {
    __shared__ float xs[1024];
    __shared__ int lrp[1025];
    __shared__ int lsrt[EPG];
    int g = blockIdx.x, tid = threadIdx.x;
    int base = g * n;
    for (int i = tid; i < n; i += 1024) xs[i] = sxws[base + i];
    for (int i = tid; i <= n; i += 1024) lrp[i] = rowptr[g * (n + 1) + i];
    __syncthreads();
    int total = lrp[n];
    for (int i = tid; i < total; i += 1024) lsrt[i] = srt[g * EPG + i];
    __syncthreads();
    if (tid < n) {
        float acc = xs[tid];                 // self loop
        int s1 = lrp[tid + 1];
        for (int j = lrp[tid]; j < s1; ++j) acc += xs[lsrt[j]];
        sagg[base + tid] = dis[base + tid] * acc;
    }
}

// ---------------- per-graph top-k via bitonic sort in LDS ----------------
__global__ __launch_bounds__(512) void k_topk(
        const float* __restrict__ sagg, const float* __restrict__ bp,
        int n, int k, int* __restrict__ perm, int* __restrict__ new_idx) {
    __shared__ unsigned long long keys[1024];
    int g = blockIdx.x, tid = threadIdx.x;
    float bp0 = bp[0];
    for (int i = tid; i < 1024; i += 512) {
        unsigned long long kv = 0ull;
        if (i < n) {
            float sc = sagg[g * n + i] + bp0;
            unsigned u  = __float_as_uint(sc);
            unsigned mk = (u & 0x80000000u) ? ~u : (u | 0x80000000u);
            kv = ((unsigned long long)mk << 32) | (unsigned)i;
        }
        keys[i] = kv;
    }
    for (int size = 2; size <= 1024; size <<= 1) {
        for (int stride = size >> 1; stride > 0; stride >>= 1) {
            __syncthreads();
            int p = tid;
            int a  = ((p / stride) * (stride << 1)) + (p & (stride - 1));
            int bx = a + stride;
            bool asc = ((a & size) == 0);
            unsigned long long ka = keys[a], kb = keys[bx];
            bool sw = asc ? (ka > kb) : (ka < kb);
            if (sw) { keys[a] = kb; keys[bx] = ka; }
        }
    }
    __syncthreads();
    for (int j = tid; j < k; j += 512) {
        int pos   = 1023 - j;
        int local = (int)(keys[pos] & 0xFFFFFFFFull);
        int oldg  = g * n + local;
        int newg  = g * k + j;
        perm[newg]    = oldg;
        new_idx[oldg] = newg;
    }
}

// ---------------- fused gather + tanh gate + readout ----------------
__global__ __launch_bounds__(256) void k_gather_readout(
        const float* __restrict__ h, const int* __restrict__ perm,
        const float* __restrict__ sagg, const float* __restrict__ bp,
        float* __restrict__ xn, int k, float* __restrict__ zsum) {
    int g = blockIdx.x;
    int lane = threadIdx.x & 63, w = threadIdx.x >> 6;
    float bp0 = bp[0];
    float mx = -INFINITY, sm = 0.0f;
    for (int j = w; j < k; j += 4) {
        int old = perm[g * k + j];
        float gate = tanhf(sagg[old] + bp0);
        float v = h[(size_t)old * 64 + lane] * gate;
        xn[(size_t)(g * k + j) * 64 + lane] = v;
        mx = fmaxf(mx, v); sm += v;
    }
    __shared__ float smx[4][64], ssm[4][64];
    smx[w][lane] = mx; ssm[w][lane] = sm;
    __syncthreads();
    if (w == 0) {
        for (int i = 1; i < 4; ++i) { mx = fmaxf(mx, smx[i][lane]); sm += ssm[i][lane]; }
        zsum[g * 128 + lane]      += mx;
        zsum[g * 128 + 64 + lane] += sm / (float)k;
    }
}

// ---------------- edge remap (invalid edges encoded as src=dst=-1) ----------------
__global__ void k_remap(const int* __restrict__ src, const int* __restrict__ dst,
                        const int* __restrict__ new_idx,
                        int* __restrict__ src2, int* __restrict__ dst2, int E) {
    int e = blockIdx.x * blockDim.x + threadIdx.x;
    if (e >= E) return;
    int s = src[e];
    int ns = -1, nd = -1;
    if (s >= 0) {
        ns = new_idx[s];
        nd = new_idx[dst[e]];
    }
    bool ok = (ns >= 0) && (nd >= 0);
    src2[e] = ok ? ns : -1;
    dst2[e] = ok ? nd : -1;
}

// ---------------- MLP head + log_softmax ----------------
__global__ void k_mlp(const float* __restrict__ zsum,
                      const float* __restrict__ L1w, const float* __restrict__ L1b,
                      const float* __restrict__ L2w, const float* __restrict__ L2b,
                      const float* __restrict__ L3w, const float* __restrict__ L3b,
                      float* __restrict__ out) {
    __shared__ float z[128], h1[64], h2[32], lg[10], lse;
    int g = blockIdx.x, tid = threadIdx.x;
    z[tid] = zsum[g * 128 + tid];
    __syncthreads();
    if (tid < 64) {
        float acc = L1b[tid];
        for (int i = 0; i < 128; ++i) acc = fmaf(z[i], L1w[i * 64 + tid], acc);
        h1[tid] = fmaxf(acc, 0.0f);
    }
    __syncthreads();
    if (tid < 32) {
        float acc = L2b[tid];
        for (int i = 0; i < 64; ++i) acc = fmaf(h1[i], L2w[i * 32 + tid], acc);
        h2[tid] = fmaxf(acc, 0.0f);
    }
    __syncthreads();
    if (tid < 10) {
        float acc = L3b[tid];
        for (int i = 0; i < 32; ++i) acc = fmaf(h2[i], L3w[i * 10 + tid], acc);
        lg[tid] = acc;
    }
    __syncthreads();
    if (tid == 0) {
        float m = lg[0];
        for (int i = 1; i < 10; ++i) m = fmaxf(m, lg[i]);
        float s = 0.0f;
        for (int i = 0; i < 10; ++i) s += expf(lg[i] - m);
        lse = m + logf(s);
    }
    __syncthreads();
    if (tid < 10) out[g * 10 + tid] = lg[tid] - lse;
}

// ---------------- launcher ----------------
extern "C" void kernel_launch(void* const* d_in, const int* in_sizes, int n_in,
                              void* d_out, int out_size, void* d_ws, size_t ws_size,
                              hipStream_t stream) {
    const float* x    = (const float*)d_in[0];
    const int*   esrc = (const int*)d_in[1];
    const int*   edst = (const int*)d_in[2];
    const float* W [3] = {(const float*)d_in[3],  (const float*)d_in[7],  (const float*)d_in[11]};
    const float* bb[3] = {(const float*)d_in[4],  (const float*)d_in[8],  (const float*)d_in[12]};
    const float* Wp[3] = {(const float*)d_in[5],  (const float*)d_in[9],  (const float*)d_in[13]};
    const float* bp[3] = {(const float*)d_in[6],  (const float*)d_in[10], (const float*)d_in[14]};
    const float* L1w = (const float*)d_in[15];
    const float* L1b = (const float*)d_in[16];
    const float* L2w = (const float*)d_in[17];
    const float* L2b = (const float*)d_in[18];
    const float* L3w = (const float*)d_in[19];
    const float* L3b = (const float*)d_in[20];
    float* out = (float*)d_out;

    // workspace carve (words)
    float* fws  = (float*)d_ws;
    float* bufA = fws;                   // pooled features, max B*820*64 = 6,717,440
    float* xwq  = bufA + 6717440;        // quarter-plane xws, rows*64
    float* agg  = xwq  + 8388608;        // conv output h
    float* dis  = agg  + 8388608;        // B*n
    float* sxws = dis  + BN_;
    float* sagg = sxws + BN_;
    float* zsum = sagg + BN_;            // 128*128
    int*   new_idx = (int*)(zsum + 128 * 128);
    int*   perm    = new_idx + BN_;
    int*   srcB    = perm + BN_;
    int*   dstB    = srcB + E_;
    int*   srcC    = dstB + E_;
    int*   dstC    = srcC + E_;
    int*   srt     = dstC + E_;          // sorted-by-dst local src indices (per layer)
    int*   rowptr  = srt  + E_;          // B * (n+1)
    unsigned short* wfrag = (unsigned short*)(rowptr + B_ * (N_ + 1)); // 8192 ushorts

    // allow >64KB dynamic LDS for the aggregation kernel (max n=1024: 118788B)
    hipFuncSetAttribute(reinterpret_cast<const void*>(k_agg_csr),
                        hipFuncAttributeMaxDynamicSharedMemorySize,
                        (1024 * 20 + EPG + 1025) * 4);

    hipMemsetAsync(zsum, 0, 128 * 128 * sizeof(float), stream);

    const int ks_[3] = {820, 656, 525};   // ceil(0.8*1024), ceil(0.8*820), ceil(0.8*656)
    int n = N_;
    const float* h_in = x;
    const int* cs = esrc;
    const int* cd = edst;
    int* nsrc[2] = {srcB, srcC};
    int* ndst[2] = {dstB, dstC};

    const int EB = (E_ + 255) / 256;

    for (int L = 0; L < 3; ++L) {
        int rows  = B_ * n;
        int k     = ks_[L];

        // CSR build (also computes dis)
        k_csr<<<B_, 1024, 0, stream>>>(cs, cd, srt, rowptr, dis, n);

        // conv: split-bf16 MFMA xw (pre-scaled by dis, quarter layout), then CSR agg
        k_wprep<<<1, 1024, 0, stream>>>(W[L], wfrag);
        k_xw_mfma<<<rows / 128, 256, 0, stream>>>(h_in, wfrag, dis, xwq, rows);
        k_agg_csr<<<B_ * 4, 1024, (size_t)(n * 20 + EPG + n + 1) * 4, stream>>>(
            srt, rowptr, dis, xwq, bb[L], agg, n, rows);

        // score conv (pre-scaled) + CSR aggregation
        k_score<<<(rows + 255) / 256, 256, 0, stream>>>(agg, Wp[L], dis, sxws, rows);
        k_score_csr<<<B_, 1024, 0, stream>>>(srt, rowptr, dis, sxws, sagg, n);

        // pool
        if (L < 2) hipMemsetAsync(new_idx, 0xFF, (size_t)rows * sizeof(int), stream);
        k_topk<<<B_, 512, 0, stream>>>(sagg, bp[L], n, k, perm, new_idx);
        k_gather_readout<<<B_, 256, 0, stream>>>(agg, perm, sagg, bp[L], bufA, k, zsum);
        if (L < 2) k_remap<<<EB, 256, 0, stream>>>(cs, cd, new_idx, nsrc[L], ndst[L], E_);

        // next layer
        h_in = bufA;
        n = k;
        if (L < 2) { cs = nsrc[L]; cd = ndst[L]; }
    }

    k_mlp<<<B_, 128, 0, stream>>>(zsum, L1w, L1b, L2w, L2b, L3w, L3b, out);
}

// Round 6
// 273.635 us; speedup vs baseline: 9.7509x; 1.9464x over previous
//
#include <hip/hip_runtime.h>
#include <math.h>

// Problem constants
constexpr int B_  = 128;
constexpr int N_  = 1024;
constexpr int E_  = 1048576;
constexpr int BN_ = B_ * N_;      // 131072
constexpr int EPG = E_ / B_;      // 8192 edges per graph (contiguous, preserved by remap)
constexpr int NSEG = 16;          // readout segments per graph

typedef short v8s __attribute__((ext_vector_type(8)));
typedef float v4f __attribute__((ext_vector_type(4)));

__device__ __forceinline__ unsigned bf16_rne(unsigned u) {
    return (u + 0x7FFFu + ((u >> 16) & 1u)) >> 16;
}

// ---------------- per-graph CSR build (counting sort by dst) ----------------
// Also emits dis = rsqrt(deg+1). 1 block per graph, 1024 threads.
__global__ __launch_bounds__(1024) void k_csr(
        const int* __restrict__ src, const int* __restrict__ dst,
        int* __restrict__ srt, int* __restrict__ rowptr,
        float* __restrict__ dis, int n) {
    __shared__ int cnt[1024];
    __shared__ int cur[1024];
    __shared__ int wsum[17];
    int g = blockIdx.x, tid = threadIdx.x;
    int base = g * n;
    const int eb = g * EPG;

    for (int i = tid; i < n; i += 1024) cnt[i] = 0;
    __syncthreads();
    for (int t = tid; t < EPG; t += 1024) {
        int s = src[eb + t];
        if (s >= 0) atomicAdd(&cnt[dst[eb + t] - base], 1);
    }
    __syncthreads();

    // block-wide exclusive scan of cnt[0..n) (zeros beyond n)
    int c = (tid < n) ? cnt[tid] : 0;
    int v = c;
    int lane = tid & 63, wv = tid >> 6;
    #pragma unroll
    for (int off = 1; off < 64; off <<= 1) {
        int t = __shfl_up(v, off, 64);
        if (lane >= off) v += t;
    }
    if (lane == 63) wsum[wv] = v;
    __syncthreads();
    if (tid == 0) {
        int run = 0;
        #pragma unroll
        for (int i = 0; i < 16; ++i) { int t = wsum[i]; wsum[i] = run; run += t; }
        wsum[16] = run;
    }
    __syncthreads();
    int excl = v - c + wsum[wv];
    if (tid < n) {
        cur[tid] = excl;
        rowptr[g * (n + 1) + tid] = excl;
        dis[base + tid] = rsqrtf((float)c + 1.0f);
    }
    if (tid == 0) rowptr[g * (n + 1) + n] = wsum[16];
    __syncthreads();

    // scatter local src indices grouped by dst
    for (int t = tid; t < EPG; t += 1024) {
        int s = src[eb + t];
        if (s < 0) continue;
        int pos = atomicAdd(&cur[dst[eb + t] - base], 1);
        srt[eb + pos] = s - base;
    }
}

// ---------------- W fragment prep for all 3 layers ----------------
// wf[L][((p*4 + c)*2 + kk)*64 + lane][j] : bf16 of W[kk*32+(lane>>4)*8+j][c*16+(lane&15)]
__global__ __launch_bounds__(1024) void k_wprep3(
        const float* __restrict__ W0, const float* __restrict__ W1,
        const float* __restrict__ W2, unsigned short* __restrict__ wfall) {
    const float* W = (blockIdx.x == 0) ? W0 : (blockIdx.x == 1) ? W1 : W2;
    unsigned short* wf = wfall + (size_t)blockIdx.x * 8192;
    int t = threadIdx.x;
    int l  = t & 63;
    int kk = (t >> 6) & 1;
    int c  = (t >> 7) & 3;
    int p  = (t >> 9) & 1;
    int col = c * 16 + (l & 15);
    int kbase = kk * 32 + (l >> 4) * 8;
    unsigned short o[8];
    #pragma unroll
    for (int j = 0; j < 8; ++j) {
        float w = W[(kbase + j) * 64 + col];
        unsigned u  = __float_as_uint(w);
        unsigned hi = bf16_rne(u);
        if (p == 0) o[j] = (unsigned short)hi;
        else {
            float lo = w - __uint_as_float(hi << 16);
            o[j] = (unsigned short)bf16_rne(__float_as_uint(lo));
        }
    }
    uint4 v;
    v.x = o[0] | ((unsigned)o[1] << 16);
    v.y = o[2] | ((unsigned)o[3] << 16);
    v.z = o[4] | ((unsigned)o[5] << 16);
    v.w = o[6] | ((unsigned)o[7] << 16);
    *reinterpret_cast<uint4*>(wf + (size_t)t * 8) = v;
}

// ---------------- xws = (h @ W) * dis via split-bf16 MFMA ----------------
// 256 threads = 4 waves; block covers 128 rows (2 x 16-row tiles per wave).
// Output in quarter-plane layout: xwq[(c*rows + r)*16 + col].
__global__ __launch_bounds__(256) void k_xw_mfma(
        const float* __restrict__ h, const unsigned short* __restrict__ wf,
        const float* __restrict__ dis, float* __restrict__ xwq, int rows) {
    __shared__ float hs[128][68];
    __shared__ float sdis[128];
    int tid = threadIdx.x;
    int r0 = blockIdx.x * 128;

    for (int i = tid; i < 128 * 16; i += 256) {
        int row = i >> 4, s = i & 15;
        float4 v = *reinterpret_cast<const float4*>(h + (size_t)(r0 + row) * 64 + s * 4);
        *reinterpret_cast<float4*>(&hs[row][s * 4]) = v;
    }
    if (tid < 128) sdis[tid] = dis[r0 + tid];

    int lane = tid & 63;
    v8s wh[4][2], wl[4][2];
    #pragma unroll
    for (int c = 0; c < 4; ++c) {
        #pragma unroll
        for (int kk = 0; kk < 2; ++kk) {
            wh[c][kk] = *reinterpret_cast<const v8s*>(wf + (((size_t)((0*4 + c)*2 + kk))*64 + lane)*8);
            wl[c][kk] = *reinterpret_cast<const v8s*>(wf + (((size_t)((1*4 + c)*2 + kk))*64 + lane)*8);
        }
    }
    __syncthreads();

    int wave = tid >> 6;
    int m = lane & 15, b = lane >> 4;
    #pragma unroll
    for (int t = 0; t < 2; ++t) {
        int lr0 = (wave * 2 + t) * 16;
        float f[16];
        *reinterpret_cast<float4*>(f)      = *reinterpret_cast<const float4*>(&hs[lr0 + m][b * 8]);
        *reinterpret_cast<float4*>(f + 4)  = *reinterpret_cast<const float4*>(&hs[lr0 + m][b * 8 + 4]);
        *reinterpret_cast<float4*>(f + 8)  = *reinterpret_cast<const float4*>(&hs[lr0 + m][32 + b * 8]);
        *reinterpret_cast<float4*>(f + 12) = *reinterpret_cast<const float4*>(&hs[lr0 + m][32 + b * 8 + 4]);
        v8s ah[2], al[2];
        #pragma unroll
        for (int ch = 0; ch < 2; ++ch) {
            #pragma unroll
            for (int j = 0; j < 8; ++j) {
                float x = f[ch * 8 + j];
                unsigned u  = __float_as_uint(x);
                unsigned hi = bf16_rne(u);
                float lo = x - __uint_as_float(hi << 16);
                ah[ch][j] = (short)hi;
                al[ch][j] = (short)bf16_rne(__float_as_uint(lo));
            }
        }
        float dv[4];
        #pragma unroll
        for (int reg = 0; reg < 4; ++reg) dv[reg] = sdis[lr0 + b * 4 + reg];

        #pragma unroll
        for (int c = 0; c < 4; ++c) {
            v4f acc = {0.f, 0.f, 0.f, 0.f};
            acc = __builtin_amdgcn_mfma_f32_16x16x32_bf16(ah[0], wh[c][0], acc, 0, 0, 0);
            acc = __builtin_amdgcn_mfma_f32_16x16x32_bf16(ah[1], wh[c][1], acc, 0, 0, 0);
            acc = __builtin_amdgcn_mfma_f32_16x16x32_bf16(al[0], wh[c][0], acc, 0, 0, 0);
            acc = __builtin_amdgcn_mfma_f32_16x16x32_bf16(al[1], wh[c][1], acc, 0, 0, 0);
            acc = __builtin_amdgcn_mfma_f32_16x16x32_bf16(ah[0], wl[c][0], acc, 0, 0, 0);
            acc = __builtin_amdgcn_mfma_f32_16x16x32_bf16(ah[1], wl[c][1], acc, 0, 0, 0);
            acc = __builtin_amdgcn_mfma_f32_16x16x32_bf16(al[0], wl[c][0], acc, 0, 0, 0);
            acc = __builtin_amdgcn_mfma_f32_16x16x32_bf16(al[1], wl[c][1], acc, 0, 0, 0);
            #pragma unroll
            for (int reg = 0; reg < 4; ++reg) {
                int grow = r0 + lr0 + b * 4 + reg;
                xwq[((size_t)c * rows + grow) * 16 + m] = acc[reg] * dv[reg];
            }
        }
    }
}

// ---------------- CSR edge aggregation, atomic-free ----------------
__global__ __launch_bounds__(1024) void k_agg_csr(
        const int* __restrict__ srt, const int* __restrict__ rowptr,
        const float* __restrict__ dis, const float* __restrict__ xwq,
        const float* __restrict__ bias, float* __restrict__ hout,
        int n, int rows) {
    extern __shared__ float lds[];
    float* xs  = lds;                       // n * 20
    int* lsrt  = (int*)(lds + n * 20);      // EPG
    int* lrp   = lsrt + EPG;                // n + 1
    int g = blockIdx.x >> 2, q = blockIdx.x & 3;
    int foff = q * 16;
    int tid  = threadIdx.x;
    int base = g * n;
    const float* plane = xwq + ((size_t)q * rows + base) * 16;

    for (int i = tid; i < n * 4; i += 1024) {
        int row = i >> 2, sub = i & 3;
        float4 v = *reinterpret_cast<const float4*>(plane + row * 16 + sub * 4);
        *reinterpret_cast<float4*>(xs + row * 20 + sub * 4) = v;
    }
    for (int i = tid; i <= n; i += 1024) lrp[i] = rowptr[g * (n + 1) + i];
    __syncthreads();
    int total = lrp[n];
    const int* gsrt = srt + g * EPG;
    for (int i = tid; i < total; i += 1024) lsrt[i] = gsrt[i];
    __syncthreads();

    int sub = tid & 3;
    float4 b = *reinterpret_cast<const float4*>(bias + foff + sub * 4);
    for (int row = tid >> 2; row < n; row += 256) {
        int s0 = lrp[row], s1 = lrp[row + 1];
        float4 acc = *reinterpret_cast<const float4*>(xs + row * 20 + sub * 4); // self-loop
        for (int j = s0; j < s1; ++j) {
            int s = lsrt[j];
            const float4 v = *reinterpret_cast<const float4*>(xs + s * 20 + sub * 4);
            acc.x += v.x; acc.y += v.y; acc.z += v.z; acc.w += v.w;
        }
        float dsc = dis[base + row];
        float4 o;
        o.x = fmaxf(fmaf(dsc, acc.x, b.x), 0.0f);
        o.y = fmaxf(fmaf(dsc, acc.y, b.y), 0.0f);
        o.z = fmaxf(fmaf(dsc, acc.z, b.z), 0.0f);
        o.w = fmaxf(fmaf(dsc, acc.w, b.w), 0.0f);
        *reinterpret_cast<float4*>(hout + (size_t)(base + row) * 64 + foff + sub * 4) = o;
    }
}

// ---------------- score conv: sxws = (h @ Wp) * dis ----------------
__global__ void k_score(const float* __restrict__ h, const float* __restrict__ Wp,
                        const float* __restrict__ dis, float* __restrict__ sxws, int rows) {
    __shared__ float wp[64];
    if (threadIdx.x < 64) wp[threadIdx.x] = Wp[threadIdx.x];
    __syncthreads();
    int r = blockIdx.x * blockDim.x + threadIdx.x;
    if (r >= rows) return;
    const float4* hr = reinterpret_cast<const float4*>(h + (size_t)r * 64);
    float acc = 0.0f;
    #pragma unroll
    for (int kk = 0; kk < 16; ++kk) {
        float4 v = hr[kk];
        acc += v.x * wp[4*kk] + v.y * wp[4*kk+1] + v.z * wp[4*kk+2] + v.w * wp[4*kk+3];
    }
    sxws[r] = acc * dis[r];
}

// ---------------- CSR score aggregation, atomic-free ----------------
__global__ __launch_bounds__(1024) void k_score_csr(
        const int* __restrict__ srt, const int* __restrict__ rowptr,
        const float* __restrict__ dis, const float* __restrict__ sxws,
        float* __restrict__ sagg, int n) {
    __shared__ float xs[1024];
    __shared__ int lrp[1025];
    __shared__ int lsrt[EPG];
    int g = blockIdx.x, tid = threadIdx.x;
    int base = g * n;
    for (int i = tid; i < n; i += 1024) xs[i] = sxws[base + i];
    for (int i = tid; i <= n; i += 1024) lrp[i] = rowptr[g * (n + 1) + i];
    __syncthreads();
    int total = lrp[n];
    for (int i = tid; i < total; i += 1024) lsrt[i] = srt[g * EPG + i];
    __syncthreads();
    if (tid < n) {
        float acc = xs[tid];                 // self loop
        int s1 = lrp[tid + 1];
        for (int j = lrp[tid]; j < s1; ++j) acc += xs[lsrt[j]];
        sagg[base + tid] = dis[base + tid] * acc;
    }
}

// ---------------- per-graph top-k via bitonic sort in LDS ----------------
__global__ __launch_bounds__(512) void k_topk(
        const float* __restrict__ sagg, const float* __restrict__ bp,
        int n, int k, int* __restrict__ perm, int* __restrict__ new_idx) {
    __shared__ unsigned long long keys[1024];
    int g = blockIdx.x, tid = threadIdx.x;
    float bp0 = bp[0];
    for (int i = tid; i < 1024; i += 512) {
        unsigned long long kv = 0ull;
        if (i < n) {
            float sc = sagg[g * n + i] + bp0;
            unsigned u  = __float_as_uint(sc);
            unsigned mk = (u & 0x80000000u) ? ~u : (u | 0x80000000u);
            kv = ((unsigned long long)mk << 32) | (unsigned)i;
        }
        keys[i] = kv;
    }
    for (int size = 2; size <= 1024; size <<= 1) {
        for (int stride = size >> 1; stride > 0; stride >>= 1) {
            __syncthreads();
            int p = tid;
            int a  = ((p / stride) * (stride << 1)) + (p & (stride - 1));
            int bx = a + stride;
            bool asc = ((a & size) == 0);
            unsigned long long ka = keys[a], kb = keys[bx];
            bool sw = asc ? (ka > kb) : (ka < kb);
            if (sw) { keys[a] = kb; keys[bx] = ka; }
        }
    }
    __syncthreads();
    for (int j = tid; j < k; j += 512) {
        int pos   = 1023 - j;
        int local = (int)(keys[pos] & 0xFFFFFFFFull);
        int oldg  = g * n + local;
        int newg  = g * k + j;
        perm[newg]    = oldg;
        new_idx[oldg] = newg;
    }
}

// ---------------- gather + tanh gate + partial readout (segmented) ----------------
// grid = B * NSEG; each block handles <=64 pooled rows of one graph.
__global__ __launch_bounds__(256) void k_gather_part(
        const float* __restrict__ h, const int* __restrict__ perm,
        const float* __restrict__ sagg, const float* __restrict__ bp,
        float* __restrict__ xn, int k, float* __restrict__ pz) {
    int g = blockIdx.x / NSEG, seg = blockIdx.x % NSEG;
    int ck = (k + NSEG - 1) / NSEG;
    int j0 = seg * ck;
    int j1 = min(k, j0 + ck);
    __shared__ float gate[64];
    __shared__ int   lperm[64];
    int tid = threadIdx.x;
    float bp0 = bp[0];
    for (int j = j0 + tid; j < j1; j += 256) {
        int old = perm[g * k + j];
        lperm[j - j0] = old;
        gate[j - j0]  = tanhf(sagg[old] + bp0);
    }
    __syncthreads();
    int lane = tid & 63, w = tid >> 6;
    float mx = -INFINITY, sm = 0.0f;
    for (int j = j0 + w; j < j1; j += 4) {
        int old = lperm[j - j0];
        float v = h[(size_t)old * 64 + lane] * gate[j - j0];
        xn[(size_t)(g * k + j) * 64 + lane] = v;
        mx = fmaxf(mx, v); sm += v;
    }
    __shared__ float smx[4][64], ssm[4][64];
    smx[w][lane] = mx; ssm[w][lane] = sm;
    __syncthreads();
    if (w == 0) {
        #pragma unroll
        for (int i = 1; i < 4; ++i) { mx = fmaxf(mx, smx[i][lane]); sm += ssm[i][lane]; }
        float* p = pz + ((size_t)g * NSEG + seg) * 128;
        p[lane]      = mx;
        p[64 + lane] = sm;
    }
}

// ---------------- combine partial readouts into zsum ----------------
__global__ __launch_bounds__(128) void k_combine(const float* __restrict__ pz,
                                                 int k, float* __restrict__ zsum) {
    int g = blockIdx.x, tid = threadIdx.x;
    const float* p = pz + (size_t)g * NSEG * 128;
    if (tid < 64) {
        float mx = -INFINITY;
        #pragma unroll
        for (int s = 0; s < NSEG; ++s) mx = fmaxf(mx, p[s * 128 + tid]);
        zsum[g * 128 + tid] += mx;
    } else {
        float sm = 0.0f;
        int f = tid - 64;
        #pragma unroll
        for (int s = 0; s < NSEG; ++s) sm += p[s * 128 + 64 + f];
        zsum[g * 128 + 64 + f] += sm / (float)k;
    }
}

// ---------------- edge remap (invalid edges encoded as src=dst=-1) ----------------
__global__ void k_remap(const int* __restrict__ src, const int* __restrict__ dst,
                        const int* __restrict__ new_idx,
                        int* __restrict__ src2, int* __restrict__ dst2, int E) {
    int e = blockIdx.x * blockDim.x + threadIdx.x;
    if (e >= E) return;
    int s = src[e];
    int ns = -1, nd = -1;
    if (s >= 0) {
        ns = new_idx[s];
        nd = new_idx[dst[e]];
    }
    bool ok = (ns >= 0) && (nd >= 0);
    src2[e] = ok ? ns : -1;
    dst2[e] = ok ? nd : -1;
}

// ---------------- MLP head + log_softmax ----------------
__global__ void k_mlp(const float* __restrict__ zsum,
                      const float* __restrict__ L1w, const float* __restrict__ L1b,
                      const float* __restrict__ L2w, const float* __restrict__ L2b,
                      const float* __restrict__ L3w, const float* __restrict__ L3b,
                      float* __restrict__ out) {
    __shared__ float z[128], h1[64], h2[32], lg[10], lse;
    int g = blockIdx.x, tid = threadIdx.x;
    z[tid] = zsum[g * 128 + tid];
    __syncthreads();
    if (tid < 64) {
        float acc = L1b[tid];
        for (int i = 0; i < 128; ++i) acc = fmaf(z[i], L1w[i * 64 + tid], acc);
        h1[tid] = fmaxf(acc, 0.0f);
    }
    __syncthreads();
    if (tid < 32) {
        float acc = L2b[tid];
        for (int i = 0; i < 64; ++i) acc = fmaf(h1[i], L2w[i * 32 + tid], acc);
        h2[tid] = fmaxf(acc, 0.0f);
    }
    __syncthreads();
    if (tid < 10) {
        float acc = L3b[tid];
        for (int i = 0; i < 32; ++i) acc = fmaf(h2[i], L3w[i * 10 + tid], acc);
        lg[tid] = acc;
    }
    __syncthreads();
    if (tid == 0) {
        float m = lg[0];
        for (int i = 1; i < 10; ++i) m = fmaxf(m, lg[i]);
        float s = 0.0f;
        for (int i = 0; i < 10; ++i) s += expf(lg[i] - m);
        lse = m + logf(s);
    }
    __syncthreads();
    if (tid < 10) out[g * 10 + tid] = lg[tid] - lse;
}

// ---------------- launcher ----------------
extern "C" void kernel_launch(void* const* d_in, const int* in_sizes, int n_in,
                              void* d_out, int out_size, void* d_ws, size_t ws_size,
                              hipStream_t stream) {
    const float* x    = (const float*)d_in[0];
    const int*   esrc = (const int*)d_in[1];
    const int*   edst = (const int*)d_in[2];
    const float* W [3] = {(const float*)d_in[3],  (const float*)d_in[7],  (const float*)d_in[11]};
    const float* bb[3] = {(const float*)d_in[4],  (const float*)d_in[8],  (const float*)d_in[12]};
    const float* Wp[3] = {(const float*)d_in[5],  (const float*)d_in[9],  (const float*)d_in[13]};
    const float* bp[3] = {(const float*)d_in[6],  (const float*)d_in[10], (const float*)d_in[14]};
    const float* L1w = (const float*)d_in[15];
    const float* L1b = (const float*)d_in[16];
    const float* L2w = (const float*)d_in[17];
    const float* L2b = (const float*)d_in[18];
    const float* L3w = (const float*)d_in[19];
    const float* L3b = (const float*)d_in[20];
    float* out = (float*)d_out;

    // workspace carve (words)
    float* fws  = (float*)d_ws;
    float* bufA = fws;                   // pooled features, max B*820*64 = 6,717,440
    float* xwq  = bufA + 6717440;        // quarter-plane xws, rows*64
    float* agg  = xwq  + 8388608;        // conv output h
    float* dis  = agg  + 8388608;        // B*n
    float* sxws = dis  + BN_;
    float* sagg = sxws + BN_;
    float* zsum = sagg + BN_;            // 128*128
    float* pz   = zsum + 128 * 128;      // B*NSEG*128 partial readouts
    int*   new_idx = (int*)(pz + B_ * NSEG * 128);
    int*   perm    = new_idx + BN_;
    int*   srcB    = perm + BN_;
    int*   dstB    = srcB + E_;
    int*   srcC    = dstB + E_;
    int*   dstC    = srcC + E_;
    int*   srt     = dstC + E_;          // sorted-by-dst local src indices (per layer)
    int*   rowptr  = srt  + E_;          // B * (n+1)
    unsigned short* wfrag = (unsigned short*)(rowptr + B_ * (N_ + 1)); // 3*8192 ushorts

    // allow >64KB dynamic LDS for the aggregation kernel (max n=1024: 118788B)
    hipFuncSetAttribute(reinterpret_cast<const void*>(k_agg_csr),
                        hipFuncAttributeMaxDynamicSharedMemorySize,
                        (1024 * 20 + EPG + 1025) * 4);

    hipMemsetAsync(zsum, 0, 128 * 128 * sizeof(float), stream);
    k_wprep3<<<3, 1024, 0, stream>>>(W[0], W[1], W[2], wfrag);

    const int ks_[3] = {820, 656, 525};   // ceil(0.8*1024), ceil(0.8*820), ceil(0.8*656)
    int n = N_;
    const float* h_in = x;
    const int* cs = esrc;
    const int* cd = edst;
    int* nsrc[2] = {srcB, srcC};
    int* ndst[2] = {dstB, dstC};

    const int EB = (E_ + 255) / 256;

    for (int L = 0; L < 3; ++L) {
        int rows  = B_ * n;
        int k     = ks_[L];

        // CSR build (also computes dis)
        k_csr<<<B_, 1024, 0, stream>>>(cs, cd, srt, rowptr, dis, n);

        // conv: split-bf16 MFMA xw (pre-scaled by dis, quarter layout), then CSR agg
        k_xw_mfma<<<rows / 128, 256, 0, stream>>>(h_in, wfrag + (size_t)L * 8192, dis, xwq, rows);
        k_agg_csr<<<B_ * 4, 1024, (size_t)(n * 20 + EPG + n + 1) * 4, stream>>>(
            srt, rowptr, dis, xwq, bb[L], agg, n, rows);

        // score conv (pre-scaled) + CSR aggregation
        k_score<<<(rows + 255) / 256, 256, 0, stream>>>(agg, Wp[L], dis, sxws, rows);
        k_score_csr<<<B_, 1024, 0, stream>>>(srt, rowptr, dis, sxws, sagg, n);

        // pool
        if (L < 2) hipMemsetAsync(new_idx, 0xFF, (size_t)rows * sizeof(int), stream);
        k_topk<<<B_, 512, 0, stream>>>(sagg, bp[L], n, k, perm, new_idx);
        k_gather_part<<<B_ * NSEG, 256, 0, stream>>>(agg, perm, sagg, bp[L], bufA, k, pz);
        k_combine<<<B_, 128, 0, stream>>>(pz, k, zsum);
        if (L < 2) k_remap<<<EB, 256, 0, stream>>>(cs, cd, new_idx, nsrc[L], ndst[L], E_);

        // next layer
        h_in = bufA;
        n = k;
        if (L < 2) { cs = nsrc[L]; cd = ndst[L]; }
    }

    k_mlp<<<B_, 128, 0, stream>>>(zsum, L1w, L1b, L2w, L2b, L3w, L3b, out);
}

// Round 7
// 226.958 us; speedup vs baseline: 11.7563x; 1.2057x over previous
//
#include <hip/hip_runtime.h>
#include <math.h>

// Problem constants
constexpr int B_  = 128;
constexpr int N_  = 1024;
constexpr int E_  = 1048576;
constexpr int BN_ = B_ * N_;      // 131072
constexpr int EPG = E_ / B_;      // 8192 edges per graph (contiguous, fixed)
constexpr int NSEG = 16;          // readout segments per graph

typedef short v8s __attribute__((ext_vector_type(8)));
typedef float v4f __attribute__((ext_vector_type(4)));

__device__ __forceinline__ unsigned bf16_rne(unsigned u) {
    return (u + 0x7FFFu + ((u >> 16) & 1u)) >> 16;
}

// ---------------- per-graph CSR build from ORIGINAL edges + cumulative map ----------------
// cum==NULL: identity (layer 0). Emits srt (local new src ids grouped by new dst),
// rowptr, dis = rsqrt(deg+1). 1 block per graph.
__global__ __launch_bounds__(1024) void k_csr2(
        const int* __restrict__ src, const int* __restrict__ dst,
        const int* __restrict__ cum,
        int* __restrict__ srt, int* __restrict__ rowptr,
        float* __restrict__ dis, int n) {
    __shared__ int cnt[1024];
    __shared__ int cur[1024];
    __shared__ int cums[1024];
    __shared__ int wsum[17];
    int g = blockIdx.x, tid = threadIdx.x;
    int gb   = g * N_;            // original node base
    int base = g * n;             // current node base
    const int eb = g * EPG;

    cums[tid] = cum ? cum[gb + tid] : tid;
    cnt[tid] = 0;
    __syncthreads();
    for (int t = tid; t < EPG; t += 1024) {
        int s = cums[src[eb + t] - gb];
        int d = cums[dst[eb + t] - gb];
        if ((s | d) >= 0) atomicAdd(&cnt[d], 1);
    }
    __syncthreads();

    // block-wide exclusive scan of cnt[0..n)
    int c = (tid < n) ? cnt[tid] : 0;
    int v = c;
    int lane = tid & 63, wv = tid >> 6;
    #pragma unroll
    for (int off = 1; off < 64; off <<= 1) {
        int t = __shfl_up(v, off, 64);
        if (lane >= off) v += t;
    }
    if (lane == 63) wsum[wv] = v;
    __syncthreads();
    if (tid == 0) {
        int run = 0;
        #pragma unroll
        for (int i = 0; i < 16; ++i) { int t = wsum[i]; wsum[i] = run; run += t; }
        wsum[16] = run;
    }
    __syncthreads();
    int excl = v - c + wsum[wv];
    if (tid < n) {
        cur[tid] = excl;
        rowptr[g * (n + 1) + tid] = excl;
        dis[base + tid] = rsqrtf((float)c + 1.0f);
    }
    if (tid == 0) rowptr[g * (n + 1) + n] = wsum[16];
    __syncthreads();

    for (int t = tid; t < EPG; t += 1024) {
        int s = cums[src[eb + t] - gb];
        int d = cums[dst[eb + t] - gb];
        if ((s | d) < 0) continue;
        int pos = atomicAdd(&cur[d], 1);
        srt[eb + pos] = s;
    }
}

// ---------------- W fragment prep for all 3 layers ----------------
__global__ __launch_bounds__(1024) void k_wprep3(
        const float* __restrict__ W0, const float* __restrict__ W1,
        const float* __restrict__ W2, unsigned short* __restrict__ wfall) {
    const float* W = (blockIdx.x == 0) ? W0 : (blockIdx.x == 1) ? W1 : W2;
    unsigned short* wf = wfall + (size_t)blockIdx.x * 8192;
    int t = threadIdx.x;
    int l  = t & 63;
    int kk = (t >> 6) & 1;
    int c  = (t >> 7) & 3;
    int p  = (t >> 9) & 1;
    int col = c * 16 + (l & 15);
    int kbase = kk * 32 + (l >> 4) * 8;
    unsigned short o[8];
    #pragma unroll
    for (int j = 0; j < 8; ++j) {
        float w = W[(kbase + j) * 64 + col];
        unsigned u  = __float_as_uint(w);
        unsigned hi = bf16_rne(u);
        if (p == 0) o[j] = (unsigned short)hi;
        else {
            float lo = w - __uint_as_float(hi << 16);
            o[j] = (unsigned short)bf16_rne(__float_as_uint(lo));
        }
    }
    uint4 v;
    v.x = o[0] | ((unsigned)o[1] << 16);
    v.y = o[2] | ((unsigned)o[3] << 16);
    v.z = o[4] | ((unsigned)o[5] << 16);
    v.w = o[6] | ((unsigned)o[7] << 16);
    *reinterpret_cast<uint4*>(wf + (size_t)t * 8) = v;
}

// ---------------- xws = (gather(h)*gate @ W) * dis via split-bf16 MFMA ----------------
// perm==NULL: direct rows (layer 0). Output quarter-plane xwq[(c*rows+r)*16+col].
__global__ __launch_bounds__(256) void k_xw_mfma(
        const float* __restrict__ h, const int* __restrict__ perm,
        const float* __restrict__ ggate, const unsigned short* __restrict__ wf,
        const float* __restrict__ dis, float* __restrict__ xwq, int rows) {
    __shared__ float hs[128][68];
    __shared__ float sdis[128];
    __shared__ int   lperm[128];
    __shared__ float lgate[128];
    int tid = threadIdx.x;
    int r0 = blockIdx.x * 128;

    if (perm) {
        if (tid < 128) { lperm[tid] = perm[r0 + tid]; lgate[tid] = ggate[r0 + tid]; }
        __syncthreads();
        for (int i = tid; i < 128 * 16; i += 256) {
            int row = i >> 4, s = i & 15;
            float4 v = *reinterpret_cast<const float4*>(h + (size_t)lperm[row] * 64 + s * 4);
            float gt = lgate[row];
            v.x *= gt; v.y *= gt; v.z *= gt; v.w *= gt;
            *reinterpret_cast<float4*>(&hs[row][s * 4]) = v;
        }
    } else {
        for (int i = tid; i < 128 * 16; i += 256) {
            int row = i >> 4, s = i & 15;
            float4 v = *reinterpret_cast<const float4*>(h + (size_t)(r0 + row) * 64 + s * 4);
            *reinterpret_cast<float4*>(&hs[row][s * 4]) = v;
        }
    }
    if (tid < 128) sdis[tid] = dis[r0 + tid];

    int lane = tid & 63;
    v8s wh[4][2], wl[4][2];
    #pragma unroll
    for (int c = 0; c < 4; ++c) {
        #pragma unroll
        for (int kk = 0; kk < 2; ++kk) {
            wh[c][kk] = *reinterpret_cast<const v8s*>(wf + (((size_t)((0*4 + c)*2 + kk))*64 + lane)*8);
            wl[c][kk] = *reinterpret_cast<const v8s*>(wf + (((size_t)((1*4 + c)*2 + kk))*64 + lane)*8);
        }
    }
    __syncthreads();

    int wave = tid >> 6;
    int m = lane & 15, b = lane >> 4;
    #pragma unroll
    for (int t = 0; t < 2; ++t) {
        int lr0 = (wave * 2 + t) * 16;
        float f[16];
        *reinterpret_cast<float4*>(f)      = *reinterpret_cast<const float4*>(&hs[lr0 + m][b * 8]);
        *reinterpret_cast<float4*>(f + 4)  = *reinterpret_cast<const float4*>(&hs[lr0 + m][b * 8 + 4]);
        *reinterpret_cast<float4*>(f + 8)  = *reinterpret_cast<const float4*>(&hs[lr0 + m][32 + b * 8]);
        *reinterpret_cast<float4*>(f + 12) = *reinterpret_cast<const float4*>(&hs[lr0 + m][32 + b * 8 + 4]);
        v8s ah[2], al[2];
        #pragma unroll
        for (int ch = 0; ch < 2; ++ch) {
            #pragma unroll
            for (int j = 0; j < 8; ++j) {
                float x = f[ch * 8 + j];
                unsigned u  = __float_as_uint(x);
                unsigned hi = bf16_rne(u);
                float lo = x - __uint_as_float(hi << 16);
                ah[ch][j] = (short)hi;
                al[ch][j] = (short)bf16_rne(__float_as_uint(lo));
            }
        }
        float dv[4];
        #pragma unroll
        for (int reg = 0; reg < 4; ++reg) dv[reg] = sdis[lr0 + b * 4 + reg];

        #pragma unroll
        for (int c = 0; c < 4; ++c) {
            v4f acc = {0.f, 0.f, 0.f, 0.f};
            acc = __builtin_amdgcn_mfma_f32_16x16x32_bf16(ah[0], wh[c][0], acc, 0, 0, 0);
            acc = __builtin_amdgcn_mfma_f32_16x16x32_bf16(ah[1], wh[c][1], acc, 0, 0, 0);
            acc = __builtin_amdgcn_mfma_f32_16x16x32_bf16(al[0], wh[c][0], acc, 0, 0, 0);
            acc = __builtin_amdgcn_mfma_f32_16x16x32_bf16(al[1], wh[c][1], acc, 0, 0, 0);
            acc = __builtin_amdgcn_mfma_f32_16x16x32_bf16(ah[0], wl[c][0], acc, 0, 0, 0);
            acc = __builtin_amdgcn_mfma_f32_16x16x32_bf16(ah[1], wl[c][1], acc, 0, 0, 0);
            acc = __builtin_amdgcn_mfma_f32_16x16x32_bf16(al[0], wl[c][0], acc, 0, 0, 0);
            acc = __builtin_amdgcn_mfma_f32_16x16x32_bf16(al[1], wl[c][1], acc, 0, 0, 0);
            #pragma unroll
            for (int reg = 0; reg < 4; ++reg) {
                int grow = r0 + lr0 + b * 4 + reg;
                xwq[((size_t)c * rows + grow) * 16 + m] = acc[reg] * dv[reg];
            }
        }
    }
}

// ---------------- CSR edge aggregation + bias/ReLU + score-conv partials ----------------
__global__ __launch_bounds__(1024) void k_agg_csr(
        const int* __restrict__ srt, const int* __restrict__ rowptr,
        const float* __restrict__ dis, const float* __restrict__ xwq,
        const float* __restrict__ bias, const float* __restrict__ Wp,
        float* __restrict__ hout, float* __restrict__ sxwsq,
        int n, int rows) {
    extern __shared__ float lds[];
    float* xs  = lds;                       // n * 20
    int* lsrt  = (int*)(lds + n * 20);      // EPG
    int* lrp   = lsrt + EPG;                // n + 1
    int g = blockIdx.x >> 2, q = blockIdx.x & 3;
    int foff = q * 16;
    int tid  = threadIdx.x;
    int base = g * n;
    const float* plane = xwq + ((size_t)q * rows + base) * 16;

    for (int i = tid; i < n * 4; i += 1024) {
        int row = i >> 2, sub = i & 3;
        float4 v = *reinterpret_cast<const float4*>(plane + row * 16 + sub * 4);
        *reinterpret_cast<float4*>(xs + row * 20 + sub * 4) = v;
    }
    for (int i = tid; i <= n; i += 1024) lrp[i] = rowptr[g * (n + 1) + i];
    __syncthreads();
    int total = lrp[n];
    const int* gsrt = srt + g * EPG;
    for (int i = tid; i < total; i += 1024) lsrt[i] = gsrt[i];
    __syncthreads();

    int sub = tid & 3;
    float4 b   = *reinterpret_cast<const float4*>(bias + foff + sub * 4);
    float4 wp4 = *reinterpret_cast<const float4*>(Wp   + foff + sub * 4);
    for (int row = tid >> 2; row < n; row += 256) {
        int s0 = lrp[row], s1 = lrp[row + 1];
        float4 acc = *reinterpret_cast<const float4*>(xs + row * 20 + sub * 4); // self-loop
        for (int j = s0; j < s1; ++j) {
            int s = lsrt[j];
            const float4 v = *reinterpret_cast<const float4*>(xs + s * 20 + sub * 4);
            acc.x += v.x; acc.y += v.y; acc.z += v.z; acc.w += v.w;
        }
        float dsc = dis[base + row];
        float4 o;
        o.x = fmaxf(fmaf(dsc, acc.x, b.x), 0.0f);
        o.y = fmaxf(fmaf(dsc, acc.y, b.y), 0.0f);
        o.z = fmaxf(fmaf(dsc, acc.z, b.z), 0.0f);
        o.w = fmaxf(fmaf(dsc, acc.w, b.w), 0.0f);
        *reinterpret_cast<float4*>(hout + (size_t)(base + row) * 64 + foff + sub * 4) = o;
        // score-conv partial over this 16-feature quarter
        float part = o.x * wp4.x + o.y * wp4.y + o.z * wp4.z + o.w * wp4.w;
        part += __shfl_xor(part, 1, 64);
        part += __shfl_xor(part, 2, 64);
        if (sub == 0) sxwsq[(size_t)q * BN_ + base + row] = part;
    }
}

// ---------------- fused score aggregation + top-k + gates + cum update ----------------
// 1 block per graph, 1024 threads. do_compose: 0 none, 1 identity-init, 2 chained.
__global__ __launch_bounds__(1024) void k_score_topk(
        const int* __restrict__ srt, const int* __restrict__ rowptr,
        const float* __restrict__ dis, const float* __restrict__ sxwsq,
        const float* __restrict__ bp, int n, int k,
        int* __restrict__ perm, float* __restrict__ ggate,
        int* __restrict__ cum, int do_compose) {
    __shared__ float xs[1024];
    __shared__ int   lrp[1025];
    __shared__ int   lsrt[EPG];              // re-used as sort keys after CSR phase
    unsigned long long* keys = (unsigned long long*)lsrt;
    int* mark = (int*)xs;                    // re-used after sagg phase
    int g = blockIdx.x, tid = threadIdx.x;
    int base = g * n;
    float bp0 = bp[0];

    if (tid < n) {
        float s0 = sxwsq[0 * (size_t)BN_ + base + tid] + sxwsq[1 * (size_t)BN_ + base + tid]
                 + sxwsq[2 * (size_t)BN_ + base + tid] + sxwsq[3 * (size_t)BN_ + base + tid];
        xs[tid] = s0 * dis[base + tid];      // pre-scaled neighbor/self message
    }
    for (int i = tid; i <= n; i += 1024) lrp[i] = rowptr[g * (n + 1) + i];
    __syncthreads();
    int total = lrp[n];
    for (int i = tid; i < total; i += 1024) lsrt[i] = srt[g * EPG + i];
    __syncthreads();

    float sag = 0.0f;
    if (tid < n) {
        float acc = xs[tid];                 // self loop
        int s1 = lrp[tid + 1];
        for (int j = lrp[tid]; j < s1; ++j) acc += xs[lsrt[j]];
        sag = dis[base + tid] * acc + bp0;   // score incl. bias
    }
    __syncthreads();                          // done with xs + lsrt contents

    {
        unsigned long long kv = 0ull;
        if (tid < n) {
            unsigned u  = __float_as_uint(sag);
            unsigned mk = (u & 0x80000000u) ? ~u : (u | 0x80000000u);
            kv = ((unsigned long long)mk << 32) | (unsigned)tid;
        }
        keys[tid] = kv;
        mark[tid] = -1;
    }

    for (int size = 2; size <= 1024; size <<= 1) {
        for (int stride = size >> 1; stride > 0; stride >>= 1) {
            __syncthreads();
            if (tid < 512) {
                int a  = ((tid / stride) * (stride << 1)) + (tid & (stride - 1));
                int bx = a + stride;
                bool asc = ((a & size) == 0);
                unsigned long long ka = keys[a], kb = keys[bx];
                bool sw = asc ? (ka > kb) : (ka < kb);
                if (sw) { keys[a] = kb; keys[bx] = ka; }
            }
        }
    }
    __syncthreads();

    if (tid < k) {
        int j = tid;                          // k <= 1024: one thread per slot
        unsigned long long kv = keys[1023 - j];
        int local   = (int)(kv & 0xFFFFFFFFull);
        unsigned mk = (unsigned)(kv >> 32);
        unsigned u  = (mk & 0x80000000u) ? (mk ^ 0x80000000u) : ~mk;
        int newg = g * k + j;
        perm[newg]  = base + local;
        ggate[newg] = tanhf(__uint_as_float(u));
        mark[local] = j;
    }
    __syncthreads();
    if (do_compose) {
        int gb = g * N_;
        int c = (do_compose == 1) ? tid : cum[gb + tid];
        cum[gb + tid] = (c >= 0) ? mark[c] : -1;
    }
}

// ---------------- segmented readout (max + sum partials), no materialization ----------------
__global__ __launch_bounds__(256) void k_readout_seg(
        const float* __restrict__ h, const int* __restrict__ perm,
        const float* __restrict__ ggate, int k, float* __restrict__ pz) {
    int g = blockIdx.x / NSEG, seg = blockIdx.x % NSEG;
    int ck = (k + NSEG - 1) / NSEG;
    int j0 = seg * ck;
    int j1 = min(k, j0 + ck);
    __shared__ float gate[64];
    __shared__ int   lperm[64];
    int tid = threadIdx.x;
    for (int j = j0 + tid; j < j1; j += 256) {
        lperm[j - j0] = perm[g * k + j];
        gate[j - j0]  = ggate[g * k + j];
    }
    __syncthreads();
    int lane = tid & 63, w = tid >> 6;
    float mx = -INFINITY, sm = 0.0f;
    for (int j = j0 + w; j < j1; j += 4) {
        float v = h[(size_t)lperm[j - j0] * 64 + lane] * gate[j - j0];
        mx = fmaxf(mx, v); sm += v;
    }
    __shared__ float smx[4][64], ssm[4][64];
    smx[w][lane] = mx; ssm[w][lane] = sm;
    __syncthreads();
    if (w == 0) {
        #pragma unroll
        for (int i = 1; i < 4; ++i) { mx = fmaxf(mx, smx[i][lane]); sm += ssm[i][lane]; }
        float* p = pz + ((size_t)g * NSEG + seg) * 128;
        p[lane]      = mx;
        p[64 + lane] = sm;
    }
}

// ---------------- MLP head: reduce pz over layers/segments + log_softmax ----------------
__global__ __launch_bounds__(128) void k_mlp(const float* __restrict__ pz,
                      const float* __restrict__ L1w, const float* __restrict__ L1b,
                      const float* __restrict__ L2w, const float* __restrict__ L2b,
                      const float* __restrict__ L3w, const float* __restrict__ L3b,
                      float* __restrict__ out) {
    __shared__ float z[128], h1[64], h2[32], lg[10], lse;
    int g = blockIdx.x, tid = threadIdx.x;
    const float kinv[3] = {1.0f / 820.0f, 1.0f / 656.0f, 1.0f / 525.0f};
    float zv = 0.0f;
    if (tid < 64) {
        #pragma unroll
        for (int L = 0; L < 3; ++L) {
            const float* p = pz + (((size_t)L * B_ + g) * NSEG) * 128;
            float mx = -INFINITY;
            #pragma unroll
            for (int s = 0; s < NSEG; ++s) mx = fmaxf(mx, p[s * 128 + tid]);
            zv += mx;
        }
    } else {
        int f = tid - 64;
        #pragma unroll
        for (int L = 0; L < 3; ++L) {
            const float* p = pz + (((size_t)L * B_ + g) * NSEG) * 128;
            float sm = 0.0f;
            #pragma unroll
            for (int s = 0; s < NSEG; ++s) sm += p[s * 128 + 64 + f];
            zv += sm * kinv[L];
        }
    }
    z[tid] = zv;
    __syncthreads();
    if (tid < 64) {
        float acc = L1b[tid];
        for (int i = 0; i < 128; ++i) acc = fmaf(z[i], L1w[i * 64 + tid], acc);
        h1[tid] = fmaxf(acc, 0.0f);
    }
    __syncthreads();
    if (tid < 32) {
        float acc = L2b[tid];
        for (int i = 0; i < 64; ++i) acc = fmaf(h1[i], L2w[i * 32 + tid], acc);
        h2[tid] = fmaxf(acc, 0.0f);
    }
    __syncthreads();
    if (tid < 10) {
        float acc = L3b[tid];
        for (int i = 0; i < 32; ++i) acc = fmaf(h2[i], L3w[i * 10 + tid], acc);
        lg[tid] = acc;
    }
    __syncthreads();
    if (tid == 0) {
        float m = lg[0];
        for (int i = 1; i < 10; ++i) m = fmaxf(m, lg[i]);
        float s = 0.0f;
        for (int i = 0; i < 10; ++i) s += expf(lg[i] - m);
        lse = m + logf(s);
    }
    __syncthreads();
    if (tid < 10) out[g * 10 + tid] = lg[tid] - lse;
}

// ---------------- launcher ----------------
extern "C" void kernel_launch(void* const* d_in, const int* in_sizes, int n_in,
                              void* d_out, int out_size, void* d_ws, size_t ws_size,
                              hipStream_t stream) {
    const float* x    = (const float*)d_in[0];
    const int*   esrc = (const int*)d_in[1];
    const int*   edst = (const int*)d_in[2];
    const float* W [3] = {(const float*)d_in[3],  (const float*)d_in[7],  (const float*)d_in[11]};
    const float* bb[3] = {(const float*)d_in[4],  (const float*)d_in[8],  (const float*)d_in[12]};
    const float* Wp[3] = {(const float*)d_in[5],  (const float*)d_in[9],  (const float*)d_in[13]};
    const float* bp[3] = {(const float*)d_in[6],  (const float*)d_in[10], (const float*)d_in[14]};
    const float* L1w = (const float*)d_in[15];
    const float* L1b = (const float*)d_in[16];
    const float* L2w = (const float*)d_in[17];
    const float* L2b = (const float*)d_in[18];
    const float* L3w = (const float*)d_in[19];
    const float* L3b = (const float*)d_in[20];
    float* out = (float*)d_out;

    // workspace carve (words)
    float* fws   = (float*)d_ws;
    float* xwq   = fws;                     // quarter-plane xws, rows*64 (max BN_*64)
    float* agg   = xwq  + (size_t)BN_ * 64; // conv output h
    float* dis   = agg  + (size_t)BN_ * 64; // B*n
    float* sxwsq = dis  + BN_;              // 4 quarter score partial planes
    float* ggate = sxwsq + 4 * (size_t)BN_; // gates per pooled row
    float* pz    = ggate + BN_;             // 3*B*NSEG*128 readout partials
    int*   perm   = (int*)(pz + 3 * B_ * NSEG * 128);
    int*   cum    = perm + BN_;             // orig node -> current local id (or -1)
    int*   srt    = cum + BN_;              // CSR: src ids grouped by dst
    int*   rowptr = srt + E_;               // B * (n+1)
    unsigned short* wfrag = (unsigned short*)(rowptr + B_ * (N_ + 1)); // 3*8192

    // allow >64KB dynamic LDS for the aggregation kernel (max n=1024: 118788B)
    hipFuncSetAttribute(reinterpret_cast<const void*>(k_agg_csr),
                        hipFuncAttributeMaxDynamicSharedMemorySize,
                        (1024 * 20 + EPG + 1025) * 4);

    k_wprep3<<<3, 1024, 0, stream>>>(W[0], W[1], W[2], wfrag);

    const int ks_[3] = {820, 656, 525};   // ceil(0.8*1024), ceil(0.8*820), ceil(0.8*656)
    int n = N_;

    for (int L = 0; L < 3; ++L) {
        int rows = B_ * n;
        int k    = ks_[L];

        // CSR from original edges + cumulative node map (also computes dis)
        k_csr2<<<B_, 1024, 0, stream>>>(esrc, edst, (L == 0) ? nullptr : cum,
                                        srt, rowptr, dis, n);

        // xws = (gathered/gated h @ W) * dis via MFMA, quarter layout
        if (L == 0)
            k_xw_mfma<<<rows / 128, 256, 0, stream>>>(x, nullptr, nullptr,
                                                      wfrag, dis, xwq, rows);
        else
            k_xw_mfma<<<rows / 128, 256, 0, stream>>>(agg, perm, ggate,
                                                      wfrag + (size_t)L * 8192, dis, xwq, rows);

        // CSR aggregation + bias/ReLU + score-conv partials
        k_agg_csr<<<B_ * 4, 1024, (size_t)(n * 20 + EPG + n + 1) * 4, stream>>>(
            srt, rowptr, dis, xwq, bb[L], Wp[L], agg, sxwsq, n, rows);

        // score aggregation + top-k + gates + cum update
        k_score_topk<<<B_, 1024, 0, stream>>>(srt, rowptr, dis, sxwsq, bp[L], n, k,
                                              perm, ggate, cum, (L < 2) ? (L + 1) : 0);

        // segmented readout partials
        k_readout_seg<<<B_ * NSEG, 256, 0, stream>>>(agg, perm, ggate, k,
                                                     pz + (size_t)L * B_ * NSEG * 128);

        n = k;
    }

    k_mlp<<<B_, 128, 0, stream>>>(pz, L1w, L1b, L2w, L2b, L3w, L3b, out);
}